// Round 6
// baseline (223.645 us; speedup 1.0000x reference)
//
#include <hip/hip_runtime.h>
#include <hip/hip_bf16.h>

// Problem constants (from reference)
#define NB 2
#define NC 1024
#define NT 1536
#define NH 16
#define ND 64
#define NBT 3072   // NB*NT
#define LN_EPS 1e-5f
#define BK 32      // GEMM K-step
// attention scale folded with log2(e): softmax computed in exp2 domain
#define QS2 0.18033688011112042f   // 0.125 * log2(e)

typedef __attribute__((ext_vector_type(8))) __bf16 bf16x8;
typedef __attribute__((ext_vector_type(4))) float f32x4;
typedef __attribute__((ext_vector_type(16))) float f32x16;

__device__ __forceinline__ unsigned short f2bf(float f) {
    unsigned u = __float_as_uint(f);
    u += 0x7fffu + ((u >> 16) & 1u);   // round-to-nearest-even
    return (unsigned short)(u >> 16);
}
__device__ __forceinline__ float bf2f(unsigned short s) {
    return __uint_as_float(((unsigned)s) << 16);
}
// pack two f32 -> packed bf16x2 (compiler emits v_cvt_pk_bf16_f32)
__device__ __forceinline__ unsigned pkbf(float a, float b) {
    union { __bf16 h[2]; unsigned u; } r;
    r.h[0] = (__bf16)a; r.h[1] = (__bf16)b;
    return r.u;
}
__device__ __forceinline__ float exp2fast(float x) {
    return __builtin_amdgcn_exp2f(x);
}
__device__ __forceinline__ f32x4 mfma16(bf16x8 a, bf16x8 b, f32x4 c) {
    return __builtin_amdgcn_mfma_f32_16x16x32_bf16(a, b, c, 0, 0, 0);
}
__device__ __forceinline__ f32x16 mfma32(bf16x8 a, bf16x8 b, f32x16 c) {
    return __builtin_amdgcn_mfma_f32_32x32x16_bf16(a, b, c, 0, 0, 0);
}
__device__ __forceinline__ bf16x8 ldbf8(const unsigned short* p) {
    return *reinterpret_cast<const bf16x8*>(p);
}
// async global->LDS, 16B per lane; LDS dest = uniform base + lane*16
__device__ __forceinline__ void gload16(const void* g, void* l) {
    __builtin_amdgcn_global_load_lds(
        (const __attribute__((address_space(1))) void*)g,
        (__attribute__((address_space(3))) void*)l, 16, 0, 0);
}
#define WAITV(n) asm volatile("s_waitcnt vmcnt(" #n ")" ::: "memory")
#define BAR()    do { __builtin_amdgcn_s_barrier(); asm volatile("" ::: "memory"); } while (0)

// ---------------------------------------------------------------------------
// Convert f32 1024x1024 weights -> bf16
__global__ __launch_bounds__(256) void wcvt_kernel(
    const float* __restrict__ w0, const float* __restrict__ w1,
    const float* __restrict__ w2, const float* __restrict__ w3,
    unsigned short* __restrict__ o0, unsigned short* __restrict__ o1,
    unsigned short* __restrict__ o2, unsigned short* __restrict__ o3)
{
    const float* src; unsigned short* dst;
    switch (blockIdx.y) {
        case 0: src = w0; dst = o0; break;
        case 1: src = w1; dst = o1; break;
        case 2: src = w2; dst = o2; break;
        default: src = w3; dst = o3; break;
    }
    int i = (blockIdx.x * 256 + threadIdx.x) * 4;
    float4 v = *reinterpret_cast<const float4*>(src + i);
    ushort4 r;
    r.x = f2bf(v.x); r.y = f2bf(v.y); r.z = f2bf(v.z); r.w = f2bf(v.w);
    *reinterpret_cast<ushort4*>(dst + i) = r;
}

// ---------------------------------------------------------------------------
// Depthwise conv3 (pad 1) -> mask -> channel LayerNorm -> bf16, [bt][c]
__global__ __launch_bounds__(256) void convln_kernel(
    const float* __restrict__ x, const float* __restrict__ y, const float* __restrict__ z,
    const float* __restrict__ qw, const float* __restrict__ kw, const float* __restrict__ vw,
    const float* __restrict__ qg, const float* __restrict__ qb,
    const float* __restrict__ kgm, const float* __restrict__ kbt,
    const float* __restrict__ vg, const float* __restrict__ vb,
    const int* __restrict__ mask,
    unsigned short* __restrict__ xn, unsigned short* __restrict__ yn,
    unsigned short* __restrict__ zn)
{
    __shared__ __align__(16) unsigned short tile[16 * 1032];
    __shared__ float psum[16][17], psq[16][17];
    __shared__ float smu[16], srs[16];

    const float* src; const float* cw; const float* g; const float* be;
    unsigned short* dst;
    if (blockIdx.z == 0)      { src = x; cw = qw; g = qg;  be = qb;  dst = xn; }
    else if (blockIdx.z == 1) { src = y; cw = kw; g = kgm; be = kbt; dst = yn; }
    else                      { src = z; cw = vw; g = vg;  be = vb;  dst = zn; }

    int b  = blockIdx.y;
    int t0 = blockIdx.x * 16;
    int tid = threadIdx.x;
    int tt = tid & 15, cc = tid >> 4;
    int t = t0 + tt;
    float mval = (mask[b * NT + t] != 0) ? 1.f : 0.f;

    const float* sb = src + (size_t)b * NC * NT;
    float sum = 0.f, ssq = 0.f;
    for (int c0 = 0; c0 < NC; c0 += 16) {
        int c = c0 + cc;
        const float* xp = sb + (size_t)c * NT;
        float v0 = xp[t];
        float vm = __shfl_up(v0, 1, 16);
        float vp = __shfl_down(v0, 1, 16);
        if (tt == 0)  vm = (t > 0)      ? xp[t - 1] : 0.f;
        if (tt == 15) vp = (t + 1 < NT) ? xp[t + 1] : 0.f;
        float w0 = cw[c * 3], w1 = cw[c * 3 + 1], w2 = cw[c * 3 + 2];
        float conv = (w0 * vm + w1 * v0 + w2 * vp) * mval;
        tile[tt * 1032 + c] = f2bf(conv);
        sum += conv; ssq += conv * conv;
    }
    psum[cc][tt] = sum; psq[cc][tt] = ssq;
    __syncthreads();
    if (tid < 16) {
        float s = 0.f, q2 = 0.f;
        for (int j = 0; j < 16; ++j) { s += psum[j][tid]; q2 += psq[j][tid]; }
        float mu = s * (1.f / 1024.f);
        float var = q2 * (1.f / 1024.f) - mu * mu;
        smu[tid] = mu;
        srs[tid] = rsqrtf(var + LN_EPS);
    }
    __syncthreads();

    int c4 = tid * 4;
    float g0 = g[c4], g1 = g[c4 + 1], g2 = g[c4 + 2], g3 = g[c4 + 3];
    float e0 = be[c4], e1 = be[c4 + 1], e2 = be[c4 + 2], e3 = be[c4 + 3];
    for (int r = 0; r < 16; ++r) {
        ushort4 tv = *reinterpret_cast<const ushort4*>(&tile[r * 1032 + c4]);
        float mu = smu[r], rs = srs[r];
        ushort4 o;
        o.x = f2bf((bf2f(tv.x) - mu) * rs * g0 + e0);
        o.y = f2bf((bf2f(tv.y) - mu) * rs * g1 + e1);
        o.z = f2bf((bf2f(tv.z) - mu) * rs * g2 + e2);
        o.w = f2bf((bf2f(tv.w) - mu) * rs * g3 + e3);
        *reinterpret_cast<ushort4*>(dst + (size_t)(b * NT + t0 + r) * NC + c4) = o;
    }
}

// ---------------------------------------------------------------------------
// q/k/v projections, LDS-staged 2-phase double-buffered (m97/T3-min structure).
// grid (24, 8, 3), block 256 (4 waves, 2x2, 64x64/wave).
__global__ __launch_bounds__(256) void gemm_qkv_kernel(
    const unsigned short* __restrict__ wqb, const unsigned short* __restrict__ wkb,
    const unsigned short* __restrict__ wvb,
    const unsigned short* __restrict__ xn, const unsigned short* __restrict__ yn,
    const unsigned short* __restrict__ zn,
    const float* __restrict__ bq, const float* __restrict__ bk, const float* __restrict__ bv,
    unsigned short* __restrict__ qo, unsigned short* __restrict__ ko,
    unsigned short* __restrict__ vt)
{
    __shared__ __align__(16) unsigned short lX[2][128 * BK];  // X tile (bt rows)
    __shared__ __align__(16) unsigned short lW[2][128 * BK];  // W tile (o rows)

    int which = blockIdx.z;
    const unsigned short* W = (which == 0) ? wqb : (which == 1) ? wkb : wvb;
    const unsigned short* X = (which == 0) ? xn : (which == 1) ? yn : zn;
    const float* bias = (which == 0) ? bq : (which == 1) ? bk : bv;

    int tid = threadIdx.x;
    int lane = tid & 63, w = tid >> 6;
    int nb = blockIdx.x * 128;   // bt tile base
    int ob = blockIdx.y * 128;   // out-channel tile base

    int srow = w * 16 + (lane >> 2);
    const unsigned short* gX = X + (size_t)(nb + srow) * NC + (lane & 3) * 8;
    const unsigned short* gW = W + (size_t)(ob + srow) * NC + (lane & 3) * 8;
    unsigned short* lX0 = &lX[0][0] + w * 16 * BK;
    unsigned short* lW0 = &lW[0][0] + w * 16 * BK;

#define QKV_STAGE(buf, k0) do {                                       \
    gload16(gX + (k0),           lX0 + (buf) * 128 * BK);             \
    gload16(gX + (k0) + 64 * NC, lX0 + (buf) * 128 * BK + 64 * BK);   \
    gload16(gW + (k0),           lW0 + (buf) * 128 * BK);             \
    gload16(gW + (k0) + 64 * NC, lW0 + (buf) * 128 * BK + 64 * BK);   \
} while (0)

    int r0 = lane & 15, kg = lane >> 4;
    const unsigned short* fW = &lW[0][0] + ((w & 1)  * 64 + r0) * BK + kg * 8;
    const unsigned short* fX = &lX[0][0] + ((w >> 1) * 64 + r0) * BK + kg * 8;

    f32x4 acc[4][4];
    #pragma unroll
    for (int i = 0; i < 4; ++i)
        #pragma unroll
        for (int j = 0; j < 4; ++j) acc[i][j] = (f32x4){0.f, 0.f, 0.f, 0.f};

#define QKV_COMPUTE(buf) do {                                                  \
    bf16x8 a_[4], b_[4];                                                       \
    _Pragma("unroll") for (int i = 0; i < 4; ++i)                              \
        a_[i] = ldbf8(fW + (buf) * 128 * BK + i * 16 * BK);                    \
    _Pragma("unroll") for (int i = 0; i < 4; ++i)                              \
        b_[i] = ldbf8(fX + (buf) * 128 * BK + i * 16 * BK);                    \
    _Pragma("unroll") for (int mf = 0; mf < 4; ++mf)                           \
        _Pragma("unroll") for (int nf = 0; nf < 4; ++nf)                       \
            acc[mf][nf] = mfma16(a_[mf], b_[nf], acc[mf][nf]);                 \
} while (0)

    QKV_STAGE(0, 0);
    #pragma unroll 1
    for (int k0 = 0; k0 < NC - 2 * BK; k0 += 2 * BK) {
        QKV_STAGE(1, k0 + BK);
        WAITV(4); BAR();
        QKV_COMPUTE(0);
        BAR();
        QKV_STAGE(0, k0 + 2 * BK);
        WAITV(4); BAR();
        QKV_COMPUTE(1);
        BAR();
    }
    QKV_STAGE(1, NC - BK);
    WAITV(4); BAR();
    QKV_COMPUTE(0);
    WAITV(0); BAR();
    QKV_COMPUTE(1);

    if (which < 2) {
        unsigned short* OUT = (which == 0) ? qo : ko;
        #pragma unroll
        for (int mf = 0; mf < 4; ++mf) {
            int o0 = ob + (w & 1) * 64 + mf * 16 + kg * 4;
            float4 bz = *reinterpret_cast<const float4*>(bias + o0);
            #pragma unroll
            for (int nf = 0; nf < 4; ++nf) {
                int n = nb + (w >> 1) * 64 + nf * 16 + r0;
                ushort4 st;
                st.x = f2bf(acc[mf][nf][0] + bz.x);
                st.y = f2bf(acc[mf][nf][1] + bz.y);
                st.z = f2bf(acc[mf][nf][2] + bz.z);
                st.w = f2bf(acc[mf][nf][3] + bz.w);
                *reinterpret_cast<ushort4*>(OUT + (size_t)n * NC + o0) = st;
            }
        }
    } else {
        #pragma unroll
        for (int mf = 0; mf < 4; ++mf) {
            int o0 = ob + (w & 1) * 64 + mf * 16 + kg * 4;
            #pragma unroll
            for (int nf = 0; nf < 4; ++nf) {
                int n = nb + (w >> 1) * 64 + nf * 16 + r0;
                #pragma unroll
                for (int r = 0; r < 4; ++r)
                    vt[(size_t)(o0 + r) * NBT + n] = f2bf(acc[mf][nf][r] + bias[o0 + r]);
            }
        }
    }
#undef QKV_STAGE
#undef QKV_COMPUTE
}

// ---------------------------------------------------------------------------
// Flash attention, block-level K-split, XCD-aware block swizzle.
// grid 1536 (1-D), block 256 = 4 waves. Softmax in exp2 domain.
// PV uses a K-slot permutation applied to BOTH P and V (product-invariant):
// P's natural lane layout feeds the B-operand directly (no cross-lane moves);
// V fragments are loaded as two 8B chunks at offsets +4*hi and +8+4*hi.
__global__ __launch_bounds__(256) void attn_kernel(
    const unsigned short* __restrict__ q, const unsigned short* __restrict__ kk,
    const unsigned short* __restrict__ vt, const int* __restrict__ mask,
    unsigned short* __restrict__ oatt)
{
    __shared__ float oL[3][64][33];
    __shared__ float mL[3][64], lL[3][64];

    // XCD swizzle: all 48 q-tiles of one (b,h) stay on one XCD (T1).
    int bid = blockIdx.x;
    int virt = (bid & 7) * 192 + (bid >> 3);   // 1536/8 = 192 per XCD
    int bh = virt / 48, qt = virt - bh * 48;
    int b = bh >> 4, h = bh & 15;
    int q0 = qt * 32;

    int lane = threadIdx.x & 63;
    int w = threadIdx.x >> 6;
    int ql = lane & 31;          // q column this lane owns
    int hi = lane >> 5;          // half-wave (k/d sub-slice)

    const int* mrow = mask + b * NT;
    int valid = 0;
    #pragma unroll
    for (int i = 0; i < NT / 64; ++i)
        valid += __popcll(__ballot(mrow[lane + 64 * i] != 0));
    if (q0 >= valid) return;     // masked q rows: oatt never observed downstream
    int ntiles = (valid + 31) >> 5;

    // this wave's K-chunk [tb, te)
    int per = ntiles >> 2, rem = ntiles & 3;
    int tb = w * per + (w < rem ? w : rem);
    int te = tb + per + (w < rem ? 1 : 0);

    const unsigned short* qp = q + (size_t)(b * NT + q0 + ql) * NC + h * ND + hi * 8;
    bf16x8 qf[4];
    #pragma unroll
    for (int dd = 0; dd < 4; ++dd) qf[dd] = ldbf8(qp + dd * 16);

    const f32x16 z16 = {0.f,0.f,0.f,0.f, 0.f,0.f,0.f,0.f, 0.f,0.f,0.f,0.f, 0.f,0.f,0.f,0.f};
    f32x16 o0 = z16, o1 = z16;   // O^T: q = ql, d = blk*32 + (r&3)+8*(r>>2)+4*hi
    float m = -1e30f, l = 0.f;

    const unsigned short* kbase = kk + (size_t)(b * NT) * NC + h * ND + hi * 8;
    const unsigned short* vbase = vt + (size_t)(h * ND) * NBT + b * NT + hi * 4;

    bf16x8 kf[4];
    if (tb < te) {
        #pragma unroll
        for (int dd = 0; dd < 4; ++dd)
            kf[dd] = ldbf8(kbase + (size_t)(tb * 32 + ql) * NC + dd * 16);
    }

    for (int t = tb; t < te; ++t) {
        int kb = t * 32;
        // S^T = K Q^T (raw, unscaled): lane holds S[k-spread][q=ql], 16 regs
        f32x16 s = z16;
        #pragma unroll
        for (int dd = 0; dd < 4; ++dd) s = mfma32(kf[dd], qf[dd], s);

        if (t + 1 < te) {
            #pragma unroll
            for (int dd = 0; dd < 4; ++dd)
                kf[dd] = ldbf8(kbase + (size_t)(kb + 32 + ql) * NC + dd * 16);
        }
        // V fragments, K-permuted to match P's natural lane layout:
        // A-elem j<4 -> V[kb + ks*16 + 4*hi + j], j>=4 -> V[kb + ks*16 + 8 + 4*hi + (j-4)]
        union { unsigned long u[2]; bf16x8 v; } vf[2][2];
        #pragma unroll
        for (int d0 = 0; d0 < 2; ++d0)
            #pragma unroll
            for (int ks = 0; ks < 2; ++ks) {
                const unsigned short* vp =
                    vbase + (size_t)(d0 * 32 + ql) * NBT + kb + ks * 16;
                vf[d0][ks].u[0] = *reinterpret_cast<const unsigned long*>(vp);
                vf[d0][ks].u[1] = *reinterpret_cast<const unsigned long*>(vp + 8);
            }

        // prefix-mask on raw S (tail tiles only; uniform branch)
        if (kb + 32 > valid) {
            #pragma unroll
            for (int r = 0; r < 16; ++r) {
                int kg = kb + (r & 3) + 8 * (r >> 2) + 4 * hi;
                if (kg >= valid) s[r] = -1e30f;
            }
        }
        // tree max over the lane's 16 raw values, then cross-half exchange
        float mx = fmaxf(fmaxf(fmaxf(s[0], s[1]), fmaxf(s[2], s[3])),
                         fmaxf(fmaxf(s[4], s[5]), fmaxf(s[6], s[7])));
        float my = fmaxf(fmaxf(fmaxf(s[8], s[9]), fmaxf(s[10], s[11])),
                         fmaxf(fmaxf(s[12], s[13]), fmaxf(s[14], s[15])));
        float pmax = fmaxf(mx, my);
        pmax = fmaxf(pmax, __shfl_xor(pmax, 32));
        float pm = pmax * QS2;   // into scaled (exp2) domain

        if (__any(pm > m)) {           // defer-max: skip rescale when possible
            float mn = fmaxf(m, pm);
            float scale = exp2fast(m - mn);
            m = mn;
            l *= scale;
            o0 *= scale; o1 *= scale;
        }

        // P = exp2(S*QS2 - m): one fma + one exp2 per element
        float negm = -m;
        float p[16];
        #pragma unroll
        for (int i = 0; i < 16; ++i)
            p[i] = exp2fast(__builtin_fmaf(s[i], QS2, negm));
        // tree row-sum + cross-half exchange
        float r0s = (p[0] + p[1]) + (p[2] + p[3]);
        float r1s = (p[4] + p[5]) + (p[6] + p[7]);
        float r2s = (p[8] + p[9]) + (p[10] + p[11]);
        float r3s = (p[12] + p[13]) + (p[14] + p[15]);
        float rs = (r0s + r1s) + (r2s + r3s);
        rs += __shfl_xor(rs, 32);
        l += rs;

        // pack to bf16 pairs; feed B-operand DIRECTLY (K-permutation matches V)
        union { unsigned u[4]; bf16x8 v; } A0, A1;
        A0.u[0] = pkbf(p[0],  p[1]);  A0.u[1] = pkbf(p[2],  p[3]);
        A0.u[2] = pkbf(p[4],  p[5]);  A0.u[3] = pkbf(p[6],  p[7]);
        A1.u[0] = pkbf(p[8],  p[9]);  A1.u[1] = pkbf(p[10], p[11]);
        A1.u[2] = pkbf(p[12], p[13]); A1.u[3] = pkbf(p[14], p[15]);

        o0 = mfma32(vf[0][0].v, A0.v, o0);
        o0 = mfma32(vf[0][1].v, A1.v, o0);
        o1 = mfma32(vf[1][0].v, A0.v, o1);
        o1 = mfma32(vf[1][1].v, A1.v, o1);
    }

    // merge the 4 partial flash states: waves 1..3 publish, wave 0 reduces
    if (w > 0) {
        int wi = w - 1;
        #pragma unroll
        for (int r = 0; r < 16; ++r) {
            oL[wi][lane][r]      = o0[r];
            oL[wi][lane][16 + r] = o1[r];
        }
        mL[wi][lane] = m;
        lL[wi][lane] = l;
    }
    __syncthreads();
    if (w > 0) return;

    float M = m;
    float mw[3], lw[3];
    #pragma unroll
    for (int j = 0; j < 3; ++j) {
        mw[j] = mL[j][lane];
        lw[j] = lL[j][lane];
        M = fmaxf(M, mw[j]);
    }
    float s0 = exp2fast(m - M);
    float L = l * s0;
    o0 *= s0; o1 *= s0;
    #pragma unroll
    for (int j = 0; j < 3; ++j) {
        float sj = exp2fast(mw[j] - M);
        L += lw[j] * sj;
        #pragma unroll
        for (int r = 0; r < 16; ++r) {
            o0[r] += sj * oL[j][lane][r];
            o1[r] += sj * oL[j][lane][16 + r];
        }
    }

    float inv = (L > 0.f) ? (1.f / L) : 0.f;
    unsigned short* ob = oatt + (size_t)(b * NT + q0 + ql) * NC + h * ND;
    #pragma unroll
    for (int g = 0; g < 4; ++g) {
        ushort4 s0v, s1v;
        s0v.x = f2bf(o0[4 * g + 0] * inv); s0v.y = f2bf(o0[4 * g + 1] * inv);
        s0v.z = f2bf(o0[4 * g + 2] * inv); s0v.w = f2bf(o0[4 * g + 3] * inv);
        s1v.x = f2bf(o1[4 * g + 0] * inv); s1v.y = f2bf(o1[4 * g + 1] * inv);
        s1v.z = f2bf(o1[4 * g + 2] * inv); s1v.w = f2bf(o1[4 * g + 3] * inv);
        *reinterpret_cast<ushort4*>(ob + g * 8 + 4 * hi)      = s0v;
        *reinterpret_cast<ushort4*>(ob + 32 + g * 8 + 4 * hi) = s1v;
    }
}

// ---------------------------------------------------------------------------
// Output projection, LDS-staged 2-phase; stores contiguous along T, fused mask.
// grid (24, 8), block 256.
__global__ __launch_bounds__(256) void gemm_out_kernel(
    const unsigned short* __restrict__ oatt, const unsigned short* __restrict__ wpb,
    const float* __restrict__ bp, const int* __restrict__ mask,
    float* __restrict__ out)
{
    __shared__ __align__(16) unsigned short lA[2][128 * BK];  // oatt tile (bt rows)
    __shared__ __align__(16) unsigned short lB[2][128 * BK];  // wp tile (o rows)

    int tid = threadIdx.x;
    int lane = tid & 63, w = tid >> 6;
    int mb  = blockIdx.x * 128;  // bt tile base
    int obb = blockIdx.y * 128;  // out-channel tile base

    int srow = w * 16 + (lane >> 2);
    const unsigned short* gA = oatt + (size_t)(mb + srow) * NC + (lane & 3) * 8;
    const unsigned short* gB = wpb + (size_t)(obb + srow) * NC + (lane & 3) * 8;
    unsigned short* lA0 = &lA[0][0] + w * 16 * BK;
    unsigned short* lB0 = &lB[0][0] + w * 16 * BK;

#define OUT_STAGE(buf, k0) do {                                       \
    gload16(gA + (k0),           lA0 + (buf) * 128 * BK);             \
    gload16(gA + (k0) + 64 * NC, lA0 + (buf) * 128 * BK + 64 * BK);   \
    gload16(gB + (k0),           lB0 + (buf) * 128 * BK);             \
    gload16(gB + (k0) + 64 * NC, lB0 + (buf) * 128 * BK + 64 * BK);   \
} while (0)

    int r0 = lane & 15, kg = lane >> 4;
    const unsigned short* fA = &lA[0][0] + ((w >> 1) * 64 + r0) * BK + kg * 8;
    const unsigned short* fB = &lB[0][0] + ((w & 1)  * 64 + r0) * BK + kg * 8;

    f32x4 acc[4][4];
    #pragma unroll
    for (int i = 0; i < 4; ++i)
        #pragma unroll
        for (int j = 0; j < 4; ++j) acc[i][j] = (f32x4){0.f, 0.f, 0.f, 0.f};

#define OUT_COMPUTE(buf) do {                                                  \
    bf16x8 a_[4], b_[4];                                                       \
    _Pragma("unroll") for (int i = 0; i < 4; ++i)                              \
        a_[i] = ldbf8(fA + (buf) * 128 * BK + i * 16 * BK);                    \
    _Pragma("unroll") for (int i = 0; i < 4; ++i)                              \
        b_[i] = ldbf8(fB + (buf) * 128 * BK + i * 16 * BK);                    \
    _Pragma("unroll") for (int mf = 0; mf < 4; ++mf)                           \
        _Pragma("unroll") for (int nf = 0; nf < 4; ++nf)                       \
            acc[mf][nf] = mfma16(a_[mf], b_[nf], acc[mf][nf]);                 \
} while (0)

    OUT_STAGE(0, 0);
    #pragma unroll 1
    for (int k0 = 0; k0 < NC - 2 * BK; k0 += 2 * BK) {
        OUT_STAGE(1, k0 + BK);
        WAITV(4); BAR();
        OUT_COMPUTE(0);
        BAR();
        OUT_STAGE(0, k0 + 2 * BK);
        WAITV(4); BAR();
        OUT_COMPUTE(1);
        BAR();
    }
    OUT_STAGE(1, NC - BK);
    WAITV(4); BAR();
    OUT_COMPUTE(0);
    WAITV(0); BAR();
    OUT_COMPUTE(1);

    int b_ = (int)(blockIdx.x >= 12);
    size_t obase = (size_t)b_ * NC * NT;
    #pragma unroll
    for (int mf = 0; mf < 4; ++mf) {
        int bt0 = mb + (w >> 1) * 64 + mf * 16 + kg * 4;
        int4 mv = *reinterpret_cast<const int4*>(mask + bt0);
        float m0 = mv.x ? 1.f : 0.f;
        float m1 = mv.y ? 1.f : 0.f;
        float m2 = mv.z ? 1.f : 0.f;
        float m3 = mv.w ? 1.f : 0.f;
        int t0 = bt0 - b_ * NT;
        #pragma unroll
        for (int nf = 0; nf < 4; ++nf) {
            int o = obb + (w & 1) * 64 + nf * 16 + r0;
            float bz = bp[o];
            f32x4 vv;
            vv[0] = (acc[mf][nf][0] + bz) * m0;
            vv[1] = (acc[mf][nf][1] + bz) * m1;
            vv[2] = (acc[mf][nf][2] + bz) * m2;
            vv[3] = (acc[mf][nf][3] + bz) * m3;
            *reinterpret_cast<f32x4*>(out + obase + (size_t)o * NT + t0) = vv;
        }
    }
#undef OUT_STAGE
#undef OUT_COMPUTE
}

// ---------------------------------------------------------------------------
__global__ __launch_bounds__(256) void maskout_kernel(const int* __restrict__ mask,
                                                      float* __restrict__ out)
{
    int i = blockIdx.x * 256 + threadIdx.x;
    if (i < NBT) out[(size_t)NB * NC * NT + i] = (mask[i] != 0) ? 1.f : 0.f;
}

// ---------------------------------------------------------------------------
extern "C" void kernel_launch(void* const* d_in, const int* in_sizes, int n_in,
                              void* d_out, int out_size, void* d_ws, size_t ws_size,
                              hipStream_t stream)
{
    const float* x    = (const float*)d_in[0];
    const float* y    = (const float*)d_in[1];
    const float* z    = (const float*)d_in[2];
    const int*   mask = (const int*)d_in[3];
    const float* qw   = (const float*)d_in[4];
    const float* kw   = (const float*)d_in[5];
    const float* vw   = (const float*)d_in[6];
    const float* qg   = (const float*)d_in[7];
    const float* qb   = (const float*)d_in[8];
    const float* kgm  = (const float*)d_in[9];
    const float* kbt  = (const float*)d_in[10];
    const float* vg   = (const float*)d_in[11];
    const float* vb   = (const float*)d_in[12];
    const float* wq   = (const float*)d_in[13];
    const float* bq   = (const float*)d_in[14];
    const float* wk   = (const float*)d_in[15];
    const float* bk   = (const float*)d_in[16];
    const float* wv   = (const float*)d_in[17];
    const float* bv   = (const float*)d_in[18];
    const float* wp   = (const float*)d_in[19];
    const float* bp   = (const float*)d_in[20];

    unsigned short* xn  = (unsigned short*)d_ws;
    unsigned short* yn  = xn + (size_t)NBT * NC;
    unsigned short* zn  = yn + (size_t)NBT * NC;
    unsigned short* qo  = zn + (size_t)NBT * NC;
    unsigned short* ko  = qo + (size_t)NBT * NC;
    unsigned short* vt  = ko + (size_t)NBT * NC;
    unsigned short* wqb = vt + (size_t)NBT * NC;
    unsigned short* wkb = wqb + (size_t)NC * NC;
    unsigned short* wvb = wkb + (size_t)NC * NC;
    unsigned short* wpb = wvb + (size_t)NC * NC;
    unsigned short* oatt = xn;  // xn dead after gemm_qkv; reuse for attention out

    float* out = (float*)d_out;

    wcvt_kernel<<<dim3(1024, 4), 256, 0, stream>>>(wq, wk, wv, wp, wqb, wkb, wvb, wpb);
    convln_kernel<<<dim3(NT / 16, NB, 3), 256, 0, stream>>>(
        x, y, z, qw, kw, vw, qg, qb, kgm, kbt, vg, vb, mask, xn, yn, zn);
    gemm_qkv_kernel<<<dim3(NBT / 128, NC / 128, 3), 256, 0, stream>>>(
        wqb, wkb, wvb, xn, yn, zn, bq, bk, bv, qo, ko, vt);
    attn_kernel<<<dim3(48 * 32), 256, 0, stream>>>(qo, ko, vt, mask, oatt);
    gemm_out_kernel<<<dim3(NBT / 128, NC / 128), 256, 0, stream>>>(oatt, wpb, bp, mask, out);
    maskout_kernel<<<dim3(NBT / 256), 256, 0, stream>>>(mask, out);
}

// Round 7
// 198.511 us; speedup vs baseline: 1.1266x; 1.1266x over previous
//
#include <hip/hip_runtime.h>
#include <hip/hip_bf16.h>

// Problem constants (from reference)
#define NB 2
#define NC 1024
#define NT 1536
#define NH 16
#define ND 64
#define NBT 3072   // NB*NT
#define LN_EPS 1e-5f
#define BK 32      // GEMM K-step
// attention scale folded with log2(e): softmax computed in exp2 domain
#define QS2 0.18033688011112042f   // 0.125 * log2(e)

typedef __attribute__((ext_vector_type(8))) __bf16 bf16x8;
typedef __attribute__((ext_vector_type(4))) float f32x4;
typedef __attribute__((ext_vector_type(16))) float f32x16;

__device__ __forceinline__ unsigned short f2bf(float f) {
    unsigned u = __float_as_uint(f);
    u += 0x7fffu + ((u >> 16) & 1u);   // round-to-nearest-even
    return (unsigned short)(u >> 16);
}
__device__ __forceinline__ float bf2f(unsigned short s) {
    return __uint_as_float(((unsigned)s) << 16);
}
// pack two f32 -> packed bf16x2 (compiler emits v_cvt_pk_bf16_f32)
__device__ __forceinline__ unsigned pkbf(float a, float b) {
    union { __bf16 h[2]; unsigned u; } r;
    r.h[0] = (__bf16)a; r.h[1] = (__bf16)b;
    return r.u;
}
__device__ __forceinline__ float exp2fast(float x) {
    return __builtin_amdgcn_exp2f(x);
}
__device__ __forceinline__ f32x4 mfma16(bf16x8 a, bf16x8 b, f32x4 c) {
    return __builtin_amdgcn_mfma_f32_16x16x32_bf16(a, b, c, 0, 0, 0);
}
__device__ __forceinline__ f32x16 mfma32(bf16x8 a, bf16x8 b, f32x16 c) {
    return __builtin_amdgcn_mfma_f32_32x32x16_bf16(a, b, c, 0, 0, 0);
}
__device__ __forceinline__ bf16x8 ldbf8(const unsigned short* p) {
    return *reinterpret_cast<const bf16x8*>(p);
}
// async global->LDS, 16B per lane; LDS dest = uniform base + lane*16
__device__ __forceinline__ void gload16(const void* g, void* l) {
    __builtin_amdgcn_global_load_lds(
        (const __attribute__((address_space(1))) void*)g,
        (__attribute__((address_space(3))) void*)l, 16, 0, 0);
}
#define WAITV(n) asm volatile("s_waitcnt vmcnt(" #n ")" ::: "memory")
#define BAR()    do { __builtin_amdgcn_s_barrier(); asm volatile("" ::: "memory"); } while (0)

// ---------------------------------------------------------------------------
// Convert f32 1024x1024 weights -> bf16
__global__ __launch_bounds__(256) void wcvt_kernel(
    const float* __restrict__ w0, const float* __restrict__ w1,
    const float* __restrict__ w2, const float* __restrict__ w3,
    unsigned short* __restrict__ o0, unsigned short* __restrict__ o1,
    unsigned short* __restrict__ o2, unsigned short* __restrict__ o3)
{
    const float* src; unsigned short* dst;
    switch (blockIdx.y) {
        case 0: src = w0; dst = o0; break;
        case 1: src = w1; dst = o1; break;
        case 2: src = w2; dst = o2; break;
        default: src = w3; dst = o3; break;
    }
    int i = (blockIdx.x * 256 + threadIdx.x) * 4;
    float4 v = *reinterpret_cast<const float4*>(src + i);
    ushort4 r;
    r.x = f2bf(v.x); r.y = f2bf(v.y); r.z = f2bf(v.z); r.w = f2bf(v.w);
    *reinterpret_cast<ushort4*>(dst + i) = r;
}

// ---------------------------------------------------------------------------
// Depthwise conv3 (pad 1) -> mask -> channel LayerNorm -> bf16, [bt][c]
__global__ __launch_bounds__(256) void convln_kernel(
    const float* __restrict__ x, const float* __restrict__ y, const float* __restrict__ z,
    const float* __restrict__ qw, const float* __restrict__ kw, const float* __restrict__ vw,
    const float* __restrict__ qg, const float* __restrict__ qb,
    const float* __restrict__ kgm, const float* __restrict__ kbt,
    const float* __restrict__ vg, const float* __restrict__ vb,
    const int* __restrict__ mask,
    unsigned short* __restrict__ xn, unsigned short* __restrict__ yn,
    unsigned short* __restrict__ zn)
{
    __shared__ __align__(16) unsigned short tile[16 * 1032];
    __shared__ float psum[16][17], psq[16][17];
    __shared__ float smu[16], srs[16];

    const float* src; const float* cw; const float* g; const float* be;
    unsigned short* dst;
    if (blockIdx.z == 0)      { src = x; cw = qw; g = qg;  be = qb;  dst = xn; }
    else if (blockIdx.z == 1) { src = y; cw = kw; g = kgm; be = kbt; dst = yn; }
    else                      { src = z; cw = vw; g = vg;  be = vb;  dst = zn; }

    int b  = blockIdx.y;
    int t0 = blockIdx.x * 16;
    int tid = threadIdx.x;
    int tt = tid & 15, cc = tid >> 4;
    int t = t0 + tt;
    float mval = (mask[b * NT + t] != 0) ? 1.f : 0.f;

    const float* sb = src + (size_t)b * NC * NT;
    float sum = 0.f, ssq = 0.f;
    for (int c0 = 0; c0 < NC; c0 += 16) {
        int c = c0 + cc;
        const float* xp = sb + (size_t)c * NT;
        float v0 = xp[t];
        float vm = __shfl_up(v0, 1, 16);
        float vp = __shfl_down(v0, 1, 16);
        if (tt == 0)  vm = (t > 0)      ? xp[t - 1] : 0.f;
        if (tt == 15) vp = (t + 1 < NT) ? xp[t + 1] : 0.f;
        float w0 = cw[c * 3], w1 = cw[c * 3 + 1], w2 = cw[c * 3 + 2];
        float conv = (w0 * vm + w1 * v0 + w2 * vp) * mval;
        tile[tt * 1032 + c] = f2bf(conv);
        sum += conv; ssq += conv * conv;
    }
    psum[cc][tt] = sum; psq[cc][tt] = ssq;
    __syncthreads();
    if (tid < 16) {
        float s = 0.f, q2 = 0.f;
        for (int j = 0; j < 16; ++j) { s += psum[j][tid]; q2 += psq[j][tid]; }
        float mu = s * (1.f / 1024.f);
        float var = q2 * (1.f / 1024.f) - mu * mu;
        smu[tid] = mu;
        srs[tid] = rsqrtf(var + LN_EPS);
    }
    __syncthreads();

    int c4 = tid * 4;
    float g0 = g[c4], g1 = g[c4 + 1], g2 = g[c4 + 2], g3 = g[c4 + 3];
    float e0 = be[c4], e1 = be[c4 + 1], e2 = be[c4 + 2], e3 = be[c4 + 3];
    for (int r = 0; r < 16; ++r) {
        ushort4 tv = *reinterpret_cast<const ushort4*>(&tile[r * 1032 + c4]);
        float mu = smu[r], rs = srs[r];
        ushort4 o;
        o.x = f2bf((bf2f(tv.x) - mu) * rs * g0 + e0);
        o.y = f2bf((bf2f(tv.y) - mu) * rs * g1 + e1);
        o.z = f2bf((bf2f(tv.z) - mu) * rs * g2 + e2);
        o.w = f2bf((bf2f(tv.w) - mu) * rs * g3 + e3);
        *reinterpret_cast<ushort4*>(dst + (size_t)(b * NT + t0 + r) * NC + c4) = o;
    }
}

// ---------------------------------------------------------------------------
// q/k/v projections, LDS-staged 2-phase double-buffered (m97/T3-min structure).
// grid (24, 8, 3), block 256 (4 waves, 2x2, 64x64/wave).
__global__ __launch_bounds__(256) void gemm_qkv_kernel(
    const unsigned short* __restrict__ wqb, const unsigned short* __restrict__ wkb,
    const unsigned short* __restrict__ wvb,
    const unsigned short* __restrict__ xn, const unsigned short* __restrict__ yn,
    const unsigned short* __restrict__ zn,
    const float* __restrict__ bq, const float* __restrict__ bk, const float* __restrict__ bv,
    unsigned short* __restrict__ qo, unsigned short* __restrict__ ko,
    unsigned short* __restrict__ vt)
{
    __shared__ __align__(16) unsigned short lX[2][128 * BK];  // X tile (bt rows)
    __shared__ __align__(16) unsigned short lW[2][128 * BK];  // W tile (o rows)

    int which = blockIdx.z;
    const unsigned short* W = (which == 0) ? wqb : (which == 1) ? wkb : wvb;
    const unsigned short* X = (which == 0) ? xn : (which == 1) ? yn : zn;
    const float* bias = (which == 0) ? bq : (which == 1) ? bk : bv;

    int tid = threadIdx.x;
    int lane = tid & 63, w = tid >> 6;
    int nb = blockIdx.x * 128;   // bt tile base
    int ob = blockIdx.y * 128;   // out-channel tile base

    int srow = w * 16 + (lane >> 2);
    const unsigned short* gX = X + (size_t)(nb + srow) * NC + (lane & 3) * 8;
    const unsigned short* gW = W + (size_t)(ob + srow) * NC + (lane & 3) * 8;
    unsigned short* lX0 = &lX[0][0] + w * 16 * BK;
    unsigned short* lW0 = &lW[0][0] + w * 16 * BK;

#define QKV_STAGE(buf, k0) do {                                       \
    gload16(gX + (k0),           lX0 + (buf) * 128 * BK);             \
    gload16(gX + (k0) + 64 * NC, lX0 + (buf) * 128 * BK + 64 * BK);   \
    gload16(gW + (k0),           lW0 + (buf) * 128 * BK);             \
    gload16(gW + (k0) + 64 * NC, lW0 + (buf) * 128 * BK + 64 * BK);   \
} while (0)

    int r0 = lane & 15, kg = lane >> 4;
    const unsigned short* fW = &lW[0][0] + ((w & 1)  * 64 + r0) * BK + kg * 8;
    const unsigned short* fX = &lX[0][0] + ((w >> 1) * 64 + r0) * BK + kg * 8;

    f32x4 acc[4][4];
    #pragma unroll
    for (int i = 0; i < 4; ++i)
        #pragma unroll
        for (int j = 0; j < 4; ++j) acc[i][j] = (f32x4){0.f, 0.f, 0.f, 0.f};

#define QKV_COMPUTE(buf) do {                                                  \
    bf16x8 a_[4], b_[4];                                                       \
    _Pragma("unroll") for (int i = 0; i < 4; ++i)                              \
        a_[i] = ldbf8(fW + (buf) * 128 * BK + i * 16 * BK);                    \
    _Pragma("unroll") for (int i = 0; i < 4; ++i)                              \
        b_[i] = ldbf8(fX + (buf) * 128 * BK + i * 16 * BK);                    \
    _Pragma("unroll") for (int mf = 0; mf < 4; ++mf)                           \
        _Pragma("unroll") for (int nf = 0; nf < 4; ++nf)                       \
            acc[mf][nf] = mfma16(a_[mf], b_[nf], acc[mf][nf]);                 \
} while (0)

    QKV_STAGE(0, 0);
    #pragma unroll 1
    for (int k0 = 0; k0 < NC - 2 * BK; k0 += 2 * BK) {
        QKV_STAGE(1, k0 + BK);
        WAITV(4); BAR();
        QKV_COMPUTE(0);
        BAR();
        QKV_STAGE(0, k0 + 2 * BK);
        WAITV(4); BAR();
        QKV_COMPUTE(1);
        BAR();
    }
    QKV_STAGE(1, NC - BK);
    WAITV(4); BAR();
    QKV_COMPUTE(0);
    WAITV(0); BAR();
    QKV_COMPUTE(1);

    if (which < 2) {
        unsigned short* OUT = (which == 0) ? qo : ko;
        #pragma unroll
        for (int mf = 0; mf < 4; ++mf) {
            int o0 = ob + (w & 1) * 64 + mf * 16 + kg * 4;
            float4 bz = *reinterpret_cast<const float4*>(bias + o0);
            #pragma unroll
            for (int nf = 0; nf < 4; ++nf) {
                int n = nb + (w >> 1) * 64 + nf * 16 + r0;
                ushort4 st;
                st.x = f2bf(acc[mf][nf][0] + bz.x);
                st.y = f2bf(acc[mf][nf][1] + bz.y);
                st.z = f2bf(acc[mf][nf][2] + bz.z);
                st.w = f2bf(acc[mf][nf][3] + bz.w);
                *reinterpret_cast<ushort4*>(OUT + (size_t)n * NC + o0) = st;
            }
        }
    } else {
        #pragma unroll
        for (int mf = 0; mf < 4; ++mf) {
            int o0 = ob + (w & 1) * 64 + mf * 16 + kg * 4;
            #pragma unroll
            for (int nf = 0; nf < 4; ++nf) {
                int n = nb + (w >> 1) * 64 + nf * 16 + r0;
                #pragma unroll
                for (int r = 0; r < 4; ++r)
                    vt[(size_t)(o0 + r) * NBT + n] = f2bf(acc[mf][nf][r] + bias[o0 + r]);
            }
        }
    }
#undef QKV_STAGE
#undef QKV_COMPUTE
}

// ---------------------------------------------------------------------------
// Flash attention, block-level K-split, BALANCED XCD-aware block swizzle:
// each XCD gets 2 b=0 heads (48q x 48k) + 2 b=1 heads (32q x 32k) -> equal
// work per XCD AND per-XCD-resident KV working set (~1.3 MB, L2-fits).
// grid 1536 (1-D), block 256 = 4 waves. Softmax in exp2 domain.
// PV uses a K-slot permutation applied to BOTH P and V (product-invariant).
__global__ __launch_bounds__(256) void attn_kernel(
    const unsigned short* __restrict__ q, const unsigned short* __restrict__ kk,
    const unsigned short* __restrict__ vt, const int* __restrict__ mask,
    unsigned short* __restrict__ oatt)
{
    __shared__ float oL[3][64][33];
    __shared__ float mL[3][64], lL[3][64];

    // balanced XCD swizzle (assumes bid%8 = XCD, evidenced by r6 FETCH drop)
    int bid = blockIdx.x;
    int xcd = bid & 7, slot = bid >> 3;        // 192 slots per XCD
    int hsel = slot / 48, qt = slot - hsel * 48;
    int bh = (hsel < 2) ? (2 * xcd + hsel) : (16 + 2 * xcd + (hsel - 2));
    int b = bh >> 4, h = bh & 15;
    int q0 = qt * 32;

    int lane = threadIdx.x & 63;
    int w = threadIdx.x >> 6;
    int ql = lane & 31;          // q column this lane owns
    int hi = lane >> 5;          // half-wave (k/d sub-slice)

    const int* mrow = mask + b * NT;
    int valid = 0;
    #pragma unroll
    for (int i = 0; i < NT / 64; ++i)
        valid += __popcll(__ballot(mrow[lane + 64 * i] != 0));
    if (q0 >= valid) return;     // masked q rows: oatt never observed downstream
    int ntiles = (valid + 31) >> 5;

    // this wave's K-chunk [tb, te)
    int per = ntiles >> 2, rem = ntiles & 3;
    int tb = w * per + (w < rem ? w : rem);
    int te = tb + per + (w < rem ? 1 : 0);

    const unsigned short* qp = q + (size_t)(b * NT + q0 + ql) * NC + h * ND + hi * 8;
    bf16x8 qf[4];
    #pragma unroll
    for (int dd = 0; dd < 4; ++dd) qf[dd] = ldbf8(qp + dd * 16);

    const f32x16 z16 = {0.f,0.f,0.f,0.f, 0.f,0.f,0.f,0.f, 0.f,0.f,0.f,0.f, 0.f,0.f,0.f,0.f};
    f32x16 o0 = z16, o1 = z16;   // O^T: q = ql, d = blk*32 + (r&3)+8*(r>>2)+4*hi
    float m = -1e30f, l = 0.f;

    const unsigned short* kbase = kk + (size_t)(b * NT) * NC + h * ND + hi * 8;
    const unsigned short* vbase = vt + (size_t)(h * ND) * NBT + b * NT + hi * 4;

    bf16x8 kf[4];
    if (tb < te) {
        #pragma unroll
        for (int dd = 0; dd < 4; ++dd)
            kf[dd] = ldbf8(kbase + (size_t)(tb * 32 + ql) * NC + dd * 16);
    }

    for (int t = tb; t < te; ++t) {
        int kb = t * 32;
        // S^T = K Q^T (raw, unscaled): lane holds S[k-spread][q=ql], 16 regs
        f32x16 s = z16;
        #pragma unroll
        for (int dd = 0; dd < 4; ++dd) s = mfma32(kf[dd], qf[dd], s);

        if (t + 1 < te) {
            #pragma unroll
            for (int dd = 0; dd < 4; ++dd)
                kf[dd] = ldbf8(kbase + (size_t)(kb + 32 + ql) * NC + dd * 16);
        }
        // V fragments, K-permuted to match P's natural lane layout:
        // A-elem j<4 -> V[kb + ks*16 + 4*hi + j], j>=4 -> V[kb + ks*16 + 8 + 4*hi + (j-4)]
        union { unsigned long u[2]; bf16x8 v; } vf[2][2];
        #pragma unroll
        for (int d0 = 0; d0 < 2; ++d0)
            #pragma unroll
            for (int ks = 0; ks < 2; ++ks) {
                const unsigned short* vp =
                    vbase + (size_t)(d0 * 32 + ql) * NBT + kb + ks * 16;
                vf[d0][ks].u[0] = *reinterpret_cast<const unsigned long*>(vp);
                vf[d0][ks].u[1] = *reinterpret_cast<const unsigned long*>(vp + 8);
            }

        // prefix-mask on raw S (tail tiles only; uniform branch)
        if (kb + 32 > valid) {
            #pragma unroll
            for (int r = 0; r < 16; ++r) {
                int kg = kb + (r & 3) + 8 * (r >> 2) + 4 * hi;
                if (kg >= valid) s[r] = -1e30f;
            }
        }
        // tree max over the lane's 16 raw values, then cross-half exchange
        float mx = fmaxf(fmaxf(fmaxf(s[0], s[1]), fmaxf(s[2], s[3])),
                         fmaxf(fmaxf(s[4], s[5]), fmaxf(s[6], s[7])));
        float my = fmaxf(fmaxf(fmaxf(s[8], s[9]), fmaxf(s[10], s[11])),
                         fmaxf(fmaxf(s[12], s[13]), fmaxf(s[14], s[15])));
        float pmax = fmaxf(mx, my);
        pmax = fmaxf(pmax, __shfl_xor(pmax, 32));
        float pm = pmax * QS2;   // into scaled (exp2) domain

        if (__any(pm > m)) {           // defer-max: skip rescale when possible
            float mn = fmaxf(m, pm);
            float scale = exp2fast(m - mn);
            m = mn;
            l *= scale;
            o0 *= scale; o1 *= scale;
        }

        // P = exp2(S*QS2 - m): one fma + one exp2 per element
        float negm = -m;
        float p[16];
        #pragma unroll
        for (int i = 0; i < 16; ++i)
            p[i] = exp2fast(__builtin_fmaf(s[i], QS2, negm));
        // tree row-sum + cross-half exchange
        float r0s = (p[0] + p[1]) + (p[2] + p[3]);
        float r1s = (p[4] + p[5]) + (p[6] + p[7]);
        float r2s = (p[8] + p[9]) + (p[10] + p[11]);
        float r3s = (p[12] + p[13]) + (p[14] + p[15]);
        float rs = (r0s + r1s) + (r2s + r3s);
        rs += __shfl_xor(rs, 32);
        l += rs;

        // pack to bf16 pairs; feed B-operand DIRECTLY (K-permutation matches V)
        union { unsigned u[4]; bf16x8 v; } A0, A1;
        A0.u[0] = pkbf(p[0],  p[1]);  A0.u[1] = pkbf(p[2],  p[3]);
        A0.u[2] = pkbf(p[4],  p[5]);  A0.u[3] = pkbf(p[6],  p[7]);
        A1.u[0] = pkbf(p[8],  p[9]);  A1.u[1] = pkbf(p[10], p[11]);
        A1.u[2] = pkbf(p[12], p[13]); A1.u[3] = pkbf(p[14], p[15]);

        o0 = mfma32(vf[0][0].v, A0.v, o0);
        o0 = mfma32(vf[0][1].v, A1.v, o0);
        o1 = mfma32(vf[1][0].v, A0.v, o1);
        o1 = mfma32(vf[1][1].v, A1.v, o1);
    }

    // merge the 4 partial flash states: waves 1..3 publish, wave 0 reduces
    if (w > 0) {
        int wi = w - 1;
        #pragma unroll
        for (int r = 0; r < 16; ++r) {
            oL[wi][lane][r]      = o0[r];
            oL[wi][lane][16 + r] = o1[r];
        }
        mL[wi][lane] = m;
        lL[wi][lane] = l;
    }
    __syncthreads();
    if (w > 0) return;

    float M = m;
    float mw[3], lw[3];
    #pragma unroll
    for (int j = 0; j < 3; ++j) {
        mw[j] = mL[j][lane];
        lw[j] = lL[j][lane];
        M = fmaxf(M, mw[j]);
    }
    float s0 = exp2fast(m - M);
    float L = l * s0;
    o0 *= s0; o1 *= s0;
    #pragma unroll
    for (int j = 0; j < 3; ++j) {
        float sj = exp2fast(mw[j] - M);
        L += lw[j] * sj;
        #pragma unroll
        for (int r = 0; r < 16; ++r) {
            o0[r] += sj * oL[j][lane][r];
            o1[r] += sj * oL[j][lane][16 + r];
        }
    }

    float inv = (L > 0.f) ? (1.f / L) : 0.f;
    unsigned short* ob = oatt + (size_t)(b * NT + q0 + ql) * NC + h * ND;
    #pragma unroll
    for (int g = 0; g < 4; ++g) {
        ushort4 s0v, s1v;
        s0v.x = f2bf(o0[4 * g + 0] * inv); s0v.y = f2bf(o0[4 * g + 1] * inv);
        s0v.z = f2bf(o0[4 * g + 2] * inv); s0v.w = f2bf(o0[4 * g + 3] * inv);
        s1v.x = f2bf(o1[4 * g + 0] * inv); s1v.y = f2bf(o1[4 * g + 1] * inv);
        s1v.z = f2bf(o1[4 * g + 2] * inv); s1v.w = f2bf(o1[4 * g + 3] * inv);
        *reinterpret_cast<ushort4*>(ob + g * 8 + 4 * hi)      = s0v;
        *reinterpret_cast<ushort4*>(ob + 32 + g * 8 + 4 * hi) = s1v;
    }
}

// ---------------------------------------------------------------------------
// Output projection, LDS-staged 2-phase; stores contiguous along T, fused mask.
// grid (24, 8), block 256.
__global__ __launch_bounds__(256) void gemm_out_kernel(
    const unsigned short* __restrict__ oatt, const unsigned short* __restrict__ wpb,
    const float* __restrict__ bp, const int* __restrict__ mask,
    float* __restrict__ out)
{
    __shared__ __align__(16) unsigned short lA[2][128 * BK];  // oatt tile (bt rows)
    __shared__ __align__(16) unsigned short lB[2][128 * BK];  // wp tile (o rows)

    int tid = threadIdx.x;
    int lane = tid & 63, w = tid >> 6;
    int mb  = blockIdx.x * 128;  // bt tile base
    int obb = blockIdx.y * 128;  // out-channel tile base

    int srow = w * 16 + (lane >> 2);
    const unsigned short* gA = oatt + (size_t)(mb + srow) * NC + (lane & 3) * 8;
    const unsigned short* gB = wpb + (size_t)(obb + srow) * NC + (lane & 3) * 8;
    unsigned short* lA0 = &lA[0][0] + w * 16 * BK;
    unsigned short* lB0 = &lB[0][0] + w * 16 * BK;

#define OUT_STAGE(buf, k0) do {                                       \
    gload16(gA + (k0),           lA0 + (buf) * 128 * BK);             \
    gload16(gA + (k0) + 64 * NC, lA0 + (buf) * 128 * BK + 64 * BK);   \
    gload16(gB + (k0),           lB0 + (buf) * 128 * BK);             \
    gload16(gB + (k0) + 64 * NC, lB0 + (buf) * 128 * BK + 64 * BK);   \
} while (0)

    int r0 = lane & 15, kg = lane >> 4;
    const unsigned short* fA = &lA[0][0] + ((w >> 1) * 64 + r0) * BK + kg * 8;
    const unsigned short* fB = &lB[0][0] + ((w & 1)  * 64 + r0) * BK + kg * 8;

    f32x4 acc[4][4];
    #pragma unroll
    for (int i = 0; i < 4; ++i)
        #pragma unroll
        for (int j = 0; j < 4; ++j) acc[i][j] = (f32x4){0.f, 0.f, 0.f, 0.f};

#define OUT_COMPUTE(buf) do {                                                  \
    bf16x8 a_[4], b_[4];                                                       \
    _Pragma("unroll") for (int i = 0; i < 4; ++i)                              \
        a_[i] = ldbf8(fA + (buf) * 128 * BK + i * 16 * BK);                    \
    _Pragma("unroll") for (int i = 0; i < 4; ++i)                              \
        b_[i] = ldbf8(fB + (buf) * 128 * BK + i * 16 * BK);                    \
    _Pragma("unroll") for (int mf = 0; mf < 4; ++mf)                           \
        _Pragma("unroll") for (int nf = 0; nf < 4; ++nf)                       \
            acc[mf][nf] = mfma16(a_[mf], b_[nf], acc[mf][nf]);                 \
} while (0)

    OUT_STAGE(0, 0);
    #pragma unroll 1
    for (int k0 = 0; k0 < NC - 2 * BK; k0 += 2 * BK) {
        OUT_STAGE(1, k0 + BK);
        WAITV(4); BAR();
        OUT_COMPUTE(0);
        BAR();
        OUT_STAGE(0, k0 + 2 * BK);
        WAITV(4); BAR();
        OUT_COMPUTE(1);
        BAR();
    }
    OUT_STAGE(1, NC - BK);
    WAITV(4); BAR();
    OUT_COMPUTE(0);
    WAITV(0); BAR();
    OUT_COMPUTE(1);

    int b_ = (int)(blockIdx.x >= 12);
    size_t obase = (size_t)b_ * NC * NT;
    #pragma unroll
    for (int mf = 0; mf < 4; ++mf) {
        int bt0 = mb + (w >> 1) * 64 + mf * 16 + kg * 4;
        int4 mv = *reinterpret_cast<const int4*>(mask + bt0);
        float m0 = mv.x ? 1.f : 0.f;
        float m1 = mv.y ? 1.f : 0.f;
        float m2 = mv.z ? 1.f : 0.f;
        float m3 = mv.w ? 1.f : 0.f;
        int t0 = bt0 - b_ * NT;
        #pragma unroll
        for (int nf = 0; nf < 4; ++nf) {
            int o = obb + (w & 1) * 64 + nf * 16 + r0;
            float bz = bp[o];
            f32x4 vv;
            vv[0] = (acc[mf][nf][0] + bz) * m0;
            vv[1] = (acc[mf][nf][1] + bz) * m1;
            vv[2] = (acc[mf][nf][2] + bz) * m2;
            vv[3] = (acc[mf][nf][3] + bz) * m3;
            *reinterpret_cast<f32x4*>(out + obase + (size_t)o * NT + t0) = vv;
        }
    }
#undef OUT_STAGE
#undef OUT_COMPUTE
}

// ---------------------------------------------------------------------------
__global__ __launch_bounds__(256) void maskout_kernel(const int* __restrict__ mask,
                                                      float* __restrict__ out)
{
    int i = blockIdx.x * 256 + threadIdx.x;
    if (i < NBT) out[(size_t)NB * NC * NT + i] = (mask[i] != 0) ? 1.f : 0.f;
}

// ---------------------------------------------------------------------------
extern "C" void kernel_launch(void* const* d_in, const int* in_sizes, int n_in,
                              void* d_out, int out_size, void* d_ws, size_t ws_size,
                              hipStream_t stream)
{
    const float* x    = (const float*)d_in[0];
    const float* y    = (const float*)d_in[1];
    const float* z    = (const float*)d_in[2];
    const int*   mask = (const int*)d_in[3];
    const float* qw   = (const float*)d_in[4];
    const float* kw   = (const float*)d_in[5];
    const float* vw   = (const float*)d_in[6];
    const float* qg   = (const float*)d_in[7];
    const float* qb   = (const float*)d_in[8];
    const float* kgm  = (const float*)d_in[9];
    const float* kbt  = (const float*)d_in[10];
    const float* vg   = (const float*)d_in[11];
    const float* vb   = (const float*)d_in[12];
    const float* wq   = (const float*)d_in[13];
    const float* bq   = (const float*)d_in[14];
    const float* wk   = (const float*)d_in[15];
    const float* bk   = (const float*)d_in[16];
    const float* wv   = (const float*)d_in[17];
    const float* bv   = (const float*)d_in[18];
    const float* wp   = (const float*)d_in[19];
    const float* bp   = (const float*)d_in[20];

    unsigned short* xn  = (unsigned short*)d_ws;
    unsigned short* yn  = xn + (size_t)NBT * NC;
    unsigned short* zn  = yn + (size_t)NBT * NC;
    unsigned short* qo  = zn + (size_t)NBT * NC;
    unsigned short* ko  = qo + (size_t)NBT * NC;
    unsigned short* vt  = ko + (size_t)NBT * NC;
    unsigned short* wqb = vt + (size_t)NBT * NC;
    unsigned short* wkb = wqb + (size_t)NC * NC;
    unsigned short* wvb = wkb + (size_t)NC * NC;
    unsigned short* wpb = wvb + (size_t)NC * NC;
    unsigned short* oatt = xn;  // xn dead after gemm_qkv; reuse for attention out

    float* out = (float*)d_out;

    wcvt_kernel<<<dim3(1024, 4), 256, 0, stream>>>(wq, wk, wv, wp, wqb, wkb, wvb, wpb);
    convln_kernel<<<dim3(NT / 16, NB, 3), 256, 0, stream>>>(
        x, y, z, qw, kw, vw, qg, qb, kgm, kbt, vg, vb, mask, xn, yn, zn);
    gemm_qkv_kernel<<<dim3(NBT / 128, NC / 128, 3), 256, 0, stream>>>(
        wqb, wkb, wvb, xn, yn, zn, bq, bk, bv, qo, ko, vt);
    attn_kernel<<<dim3(48 * 32), 256, 0, stream>>>(qo, ko, vt, mask, oatt);
    gemm_out_kernel<<<dim3(NBT / 128, NC / 128), 256, 0, stream>>>(oatt, wpb, bp, mask, out);
    maskout_kernel<<<dim3(NBT / 256), 256, 0, stream>>>(mask, out);
}

// Round 8
// 151.156 us; speedup vs baseline: 1.4796x; 1.3133x over previous
//
#include <hip/hip_runtime.h>
#include <hip/hip_bf16.h>

// Problem constants (from reference)
#define NB 2
#define NC 1024
#define NT 1536
#define NH 16
#define ND 64
#define NBT 3072   // NB*NT
#define LN_EPS 1e-5f
#define BK 32      // GEMM K-step
// attention scale folded with log2(e): softmax computed in exp2 domain
#define QS2 0.18033688011112042f   // 0.125 * log2(e)

typedef __attribute__((ext_vector_type(8))) __bf16 bf16x8;
typedef __attribute__((ext_vector_type(4))) float f32x4;
typedef __attribute__((ext_vector_type(16))) float f32x16;

__device__ __forceinline__ unsigned short f2bf(float f) {
    unsigned u = __float_as_uint(f);
    u += 0x7fffu + ((u >> 16) & 1u);   // round-to-nearest-even
    return (unsigned short)(u >> 16);
}
__device__ __forceinline__ float bf2f(unsigned short s) {
    return __uint_as_float(((unsigned)s) << 16);
}
// pack two f32 -> packed bf16x2 (compiler emits v_cvt_pk_bf16_f32)
__device__ __forceinline__ unsigned pkbf(float a, float b) {
    union { __bf16 h[2]; unsigned u; } r;
    r.h[0] = (__bf16)a; r.h[1] = (__bf16)b;
    return r.u;
}
__device__ __forceinline__ float exp2fast(float x) {
    return __builtin_amdgcn_exp2f(x);
}
__device__ __forceinline__ f32x4 mfma16(bf16x8 a, bf16x8 b, f32x4 c) {
    return __builtin_amdgcn_mfma_f32_16x16x32_bf16(a, b, c, 0, 0, 0);
}
__device__ __forceinline__ f32x16 mfma32(bf16x8 a, bf16x8 b, f32x16 c) {
    return __builtin_amdgcn_mfma_f32_32x32x16_bf16(a, b, c, 0, 0, 0);
}
__device__ __forceinline__ bf16x8 ldbf8(const unsigned short* p) {
    return *reinterpret_cast<const bf16x8*>(p);
}
// async global->LDS, 16B per lane; LDS dest = uniform base + lane*16
__device__ __forceinline__ void gload16(const void* g, void* l) {
    __builtin_amdgcn_global_load_lds(
        (const __attribute__((address_space(1))) void*)g,
        (__attribute__((address_space(3))) void*)l, 16, 0, 0);
}
#define WAITV(n) asm volatile("s_waitcnt vmcnt(" #n ")" ::: "memory")
#define BAR()    do { __builtin_amdgcn_s_barrier(); asm volatile("" ::: "memory"); } while (0)

// ---------------------------------------------------------------------------
// Fragment layouts (all 4 KB per (b,h,32-key/query tile), lane = hi*32+ql):
// q/k frag: tile*2048 + dd*512 + lane*8 + j   <- channel c = h*64+dd*16+hi*8+j
// v   frag: tile*2048 + d0*1024 + ks*512 + lane*8 + j  (K-slot permuted, see r5)
// Attn loads become fully-coalesced 1KB wave loads (kills L2 line amplification).
// ---------------------------------------------------------------------------

// Convert f32 1024x1024 weights -> bf16
__global__ __launch_bounds__(256) void wcvt_kernel(
    const float* __restrict__ w0, const float* __restrict__ w1,
    const float* __restrict__ w2, const float* __restrict__ w3,
    unsigned short* __restrict__ o0, unsigned short* __restrict__ o1,
    unsigned short* __restrict__ o2, unsigned short* __restrict__ o3)
{
    const float* src; unsigned short* dst;
    switch (blockIdx.y) {
        case 0: src = w0; dst = o0; break;
        case 1: src = w1; dst = o1; break;
        case 2: src = w2; dst = o2; break;
        default: src = w3; dst = o3; break;
    }
    int i = (blockIdx.x * 256 + threadIdx.x) * 4;
    float4 v = *reinterpret_cast<const float4*>(src + i);
    ushort4 r;
    r.x = f2bf(v.x); r.y = f2bf(v.y); r.z = f2bf(v.z); r.w = f2bf(v.w);
    *reinterpret_cast<ushort4*>(dst + i) = r;
}

// ---------------------------------------------------------------------------
// Depthwise conv3 (pad 1) -> mask -> channel LayerNorm -> bf16, [bt][c]
__global__ __launch_bounds__(256) void convln_kernel(
    const float* __restrict__ x, const float* __restrict__ y, const float* __restrict__ z,
    const float* __restrict__ qw, const float* __restrict__ kw, const float* __restrict__ vw,
    const float* __restrict__ qg, const float* __restrict__ qb,
    const float* __restrict__ kgm, const float* __restrict__ kbt,
    const float* __restrict__ vg, const float* __restrict__ vb,
    const int* __restrict__ mask,
    unsigned short* __restrict__ xn, unsigned short* __restrict__ yn,
    unsigned short* __restrict__ zn)
{
    __shared__ __align__(16) unsigned short tile[16 * 1032];
    __shared__ float psum[16][17], psq[16][17];
    __shared__ float smu[16], srs[16];

    const float* src; const float* cw; const float* g; const float* be;
    unsigned short* dst;
    if (blockIdx.z == 0)      { src = x; cw = qw; g = qg;  be = qb;  dst = xn; }
    else if (blockIdx.z == 1) { src = y; cw = kw; g = kgm; be = kbt; dst = yn; }
    else                      { src = z; cw = vw; g = vg;  be = vb;  dst = zn; }

    int b  = blockIdx.y;
    int t0 = blockIdx.x * 16;
    int tid = threadIdx.x;
    int tt = tid & 15, cc = tid >> 4;
    int t = t0 + tt;
    float mval = (mask[b * NT + t] != 0) ? 1.f : 0.f;

    const float* sb = src + (size_t)b * NC * NT;
    float sum = 0.f, ssq = 0.f;
    for (int c0 = 0; c0 < NC; c0 += 16) {
        int c = c0 + cc;
        const float* xp = sb + (size_t)c * NT;
        float v0 = xp[t];
        float vm = __shfl_up(v0, 1, 16);
        float vp = __shfl_down(v0, 1, 16);
        if (tt == 0)  vm = (t > 0)      ? xp[t - 1] : 0.f;
        if (tt == 15) vp = (t + 1 < NT) ? xp[t + 1] : 0.f;
        float w0 = cw[c * 3], w1 = cw[c * 3 + 1], w2 = cw[c * 3 + 2];
        float conv = (w0 * vm + w1 * v0 + w2 * vp) * mval;
        tile[tt * 1032 + c] = f2bf(conv);
        sum += conv; ssq += conv * conv;
    }
    psum[cc][tt] = sum; psq[cc][tt] = ssq;
    __syncthreads();
    if (tid < 16) {
        float s = 0.f, q2 = 0.f;
        for (int j = 0; j < 16; ++j) { s += psum[j][tid]; q2 += psq[j][tid]; }
        float mu = s * (1.f / 1024.f);
        float var = q2 * (1.f / 1024.f) - mu * mu;
        smu[tid] = mu;
        srs[tid] = rsqrtf(var + LN_EPS);
    }
    __syncthreads();

    int c4 = tid * 4;
    float g0 = g[c4], g1 = g[c4 + 1], g2 = g[c4 + 2], g3 = g[c4 + 3];
    float e0 = be[c4], e1 = be[c4 + 1], e2 = be[c4 + 2], e3 = be[c4 + 3];
    for (int r = 0; r < 16; ++r) {
        ushort4 tv = *reinterpret_cast<const ushort4*>(&tile[r * 1032 + c4]);
        float mu = smu[r], rs = srs[r];
        ushort4 o;
        o.x = f2bf((bf2f(tv.x) - mu) * rs * g0 + e0);
        o.y = f2bf((bf2f(tv.y) - mu) * rs * g1 + e1);
        o.z = f2bf((bf2f(tv.z) - mu) * rs * g2 + e2);
        o.w = f2bf((bf2f(tv.w) - mu) * rs * g3 + e3);
        *reinterpret_cast<ushort4*>(dst + (size_t)(b * NT + t0 + r) * NC + c4) = o;
    }
}

// ---------------------------------------------------------------------------
// q/k/v projections, LDS-staged 2-phase double-buffered. Epilogue writes
// MFMA-fragment-major layouts consumed by attn (see layout comment above).
// grid (24, 8, 3), block 256 (4 waves, 2x2, 64x64/wave).
__global__ __launch_bounds__(256) void gemm_qkv_kernel(
    const unsigned short* __restrict__ wqb, const unsigned short* __restrict__ wkb,
    const unsigned short* __restrict__ wvb,
    const unsigned short* __restrict__ xn, const unsigned short* __restrict__ yn,
    const unsigned short* __restrict__ zn,
    const float* __restrict__ bq, const float* __restrict__ bk, const float* __restrict__ bv,
    unsigned short* __restrict__ qfr, unsigned short* __restrict__ kfr,
    unsigned short* __restrict__ vfr)
{
    __shared__ __align__(16) unsigned short lX[2][128 * BK];  // X tile (bt rows)
    __shared__ __align__(16) unsigned short lW[2][128 * BK];  // W tile (o rows)

    int which = blockIdx.z;
    const unsigned short* W = (which == 0) ? wqb : (which == 1) ? wkb : wvb;
    const unsigned short* X = (which == 0) ? xn : (which == 1) ? yn : zn;
    const float* bias = (which == 0) ? bq : (which == 1) ? bk : bv;

    int tid = threadIdx.x;
    int lane = tid & 63, w = tid >> 6;
    int nb = blockIdx.x * 128;   // bt tile base
    int ob = blockIdx.y * 128;   // out-channel tile base

    int srow = w * 16 + (lane >> 2);
    const unsigned short* gX = X + (size_t)(nb + srow) * NC + (lane & 3) * 8;
    const unsigned short* gW = W + (size_t)(ob + srow) * NC + (lane & 3) * 8;
    unsigned short* lX0 = &lX[0][0] + w * 16 * BK;
    unsigned short* lW0 = &lW[0][0] + w * 16 * BK;

#define QKV_STAGE(buf, k0) do {                                       \
    gload16(gX + (k0),           lX0 + (buf) * 128 * BK);             \
    gload16(gX + (k0) + 64 * NC, lX0 + (buf) * 128 * BK + 64 * BK);   \
    gload16(gW + (k0),           lW0 + (buf) * 128 * BK);             \
    gload16(gW + (k0) + 64 * NC, lW0 + (buf) * 128 * BK + 64 * BK);   \
} while (0)

    int r0 = lane & 15, kg = lane >> 4;
    const unsigned short* fW = &lW[0][0] + ((w & 1)  * 64 + r0) * BK + kg * 8;
    const unsigned short* fX = &lX[0][0] + ((w >> 1) * 64 + r0) * BK + kg * 8;

    f32x4 acc[4][4];
    #pragma unroll
    for (int i = 0; i < 4; ++i)
        #pragma unroll
        for (int j = 0; j < 4; ++j) acc[i][j] = (f32x4){0.f, 0.f, 0.f, 0.f};

#define QKV_COMPUTE(buf) do {                                                  \
    bf16x8 a_[4], b_[4];                                                       \
    _Pragma("unroll") for (int i = 0; i < 4; ++i)                              \
        a_[i] = ldbf8(fW + (buf) * 128 * BK + i * 16 * BK);                    \
    _Pragma("unroll") for (int i = 0; i < 4; ++i)                              \
        b_[i] = ldbf8(fX + (buf) * 128 * BK + i * 16 * BK);                    \
    _Pragma("unroll") for (int mf = 0; mf < 4; ++mf)                           \
        _Pragma("unroll") for (int nf = 0; nf < 4; ++nf)                       \
            acc[mf][nf] = mfma16(a_[mf], b_[nf], acc[mf][nf]);                 \
} while (0)

    QKV_STAGE(0, 0);
    #pragma unroll 1
    for (int k0 = 0; k0 < NC - 2 * BK; k0 += 2 * BK) {
        QKV_STAGE(1, k0 + BK);
        WAITV(4); BAR();
        QKV_COMPUTE(0);
        BAR();
        QKV_STAGE(0, k0 + 2 * BK);
        WAITV(4); BAR();
        QKV_COMPUTE(1);
        BAR();
    }
    QKV_STAGE(1, NC - BK);
    WAITV(4); BAR();
    QKV_COMPUTE(0);
    WAITV(0); BAR();
    QKV_COMPUTE(1);

    if (which < 2) {
        unsigned short* OUT = (which == 0) ? qfr : kfr;
        #pragma unroll
        for (int mf = 0; mf < 4; ++mf) {
            int o0 = ob + (w & 1) * 64 + mf * 16 + kg * 4;
            int h = o0 >> 6, c0 = o0 & 63;
            int dd = c0 >> 4, hi2 = (c0 >> 3) & 1, j0 = c0 & 7;
            float4 bz = *reinterpret_cast<const float4*>(bias + o0);
            #pragma unroll
            for (int nf = 0; nf < 4; ++nf) {
                int n = nb + (w >> 1) * 64 + nf * 16 + r0;
                int b_ = (n >= NT), t = n - b_ * NT;
                int t32 = t >> 5, ql = t & 31;
                size_t addr = ((size_t)((b_ * NH + h) * 48 + t32)) * 2048
                            + dd * 512 + (hi2 * 32 + ql) * 8 + j0;
                ushort4 st;
                st.x = f2bf(acc[mf][nf][0] + bz.x);
                st.y = f2bf(acc[mf][nf][1] + bz.y);
                st.z = f2bf(acc[mf][nf][2] + bz.z);
                st.w = f2bf(acc[mf][nf][3] + bz.w);
                *reinterpret_cast<ushort4*>(OUT + addr) = st;
            }
        }
    } else {
        #pragma unroll
        for (int mf = 0; mf < 4; ++mf) {
            int o0 = ob + (w & 1) * 64 + mf * 16 + kg * 4;
            int h = o0 >> 6;
            int dch0 = o0 & 63;
            int d0 = dch0 >> 5;
            #pragma unroll
            for (int nf = 0; nf < 4; ++nf) {
                int n = nb + (w >> 1) * 64 + nf * 16 + r0;
                int b_ = (n >= NT), t = n - b_ * NT;
                int t32 = t >> 5, kloc = t & 31;
                int ks = kloc >> 4, r16 = kloc & 15;
                int hi2 = (r16 >> 2) & 1;
                int j = (r16 & 3) + 4 * (r16 >> 3);
                size_t base = ((size_t)((b_ * NH + h) * 48 + t32)) * 2048
                            + d0 * 1024 + ks * 512 + hi2 * 256 + j;
                #pragma unroll
                for (int r = 0; r < 4; ++r) {
                    int ql = (dch0 + r) & 31;
                    vfr[base + ql * 8] = f2bf(acc[mf][nf][r] + bias[o0 + r]);
                }
            }
        }
    }
#undef QKV_STAGE
#undef QKV_COMPUTE
}

// ---------------------------------------------------------------------------
// Flash attention, block-level K-split, balanced XCD swizzle (r7), fragment-
// layout Q/K/V -> every load is one fully-coalesced 1KB wave load.
// grid 1536 (1-D), block 256 = 4 waves. Softmax in exp2 domain.
__global__ __launch_bounds__(256) void attn_kernel(
    const unsigned short* __restrict__ qfr, const unsigned short* __restrict__ kfr,
    const unsigned short* __restrict__ vfr, const int* __restrict__ mask,
    unsigned short* __restrict__ oatt)
{
    __shared__ float oL[3][64][33];
    __shared__ float mL[3][64], lL[3][64];

    // balanced XCD swizzle: each XCD owns 2 b=0 heads + 2 b=1 heads
    int bid = blockIdx.x;
    int xcd = bid & 7, slot = bid >> 3;        // 192 slots per XCD
    int hsel = slot / 48, qt = slot - hsel * 48;
    int bh = (hsel < 2) ? (2 * xcd + hsel) : (16 + 2 * xcd + (hsel - 2));
    int b = bh >> 4, h = bh & 15;
    int q0 = qt * 32;

    int lane = threadIdx.x & 63;
    int w = threadIdx.x >> 6;
    int ql = lane & 31;          // q column this lane owns
    int hi = lane >> 5;          // half-wave (k/d sub-slice)

    const int* mrow = mask + b * NT;
    int valid = 0;
    #pragma unroll
    for (int i = 0; i < NT / 64; ++i)
        valid += __popcll(__ballot(mrow[lane + 64 * i] != 0));
    if (q0 >= valid) return;     // masked q rows: oatt never observed downstream
    int ntiles = (valid + 31) >> 5;

    // this wave's K-chunk [tb, te)
    int per = ntiles >> 2, rem = ntiles & 3;
    int tb = w * per + (w < rem ? w : rem);
    int te = tb + per + (w < rem ? 1 : 0);

    const unsigned short* qtile = qfr + ((size_t)(bh * 48 + qt)) * 2048;
    bf16x8 qf[4];
    #pragma unroll
    for (int dd = 0; dd < 4; ++dd) qf[dd] = ldbf8(qtile + dd * 512 + lane * 8);

    const unsigned short* kbh = kfr + (size_t)bh * 48 * 2048;
    const unsigned short* vbh = vfr + (size_t)bh * 48 * 2048;

    const f32x16 z16 = {0.f,0.f,0.f,0.f, 0.f,0.f,0.f,0.f, 0.f,0.f,0.f,0.f, 0.f,0.f,0.f,0.f};
    f32x16 o0 = z16, o1 = z16;   // O^T: q = ql, d = blk*32 + (r&3)+8*(r>>2)+4*hi
    float m = -1e30f, l = 0.f;

    bf16x8 kf[4];
    if (tb < te) {
        #pragma unroll
        for (int dd = 0; dd < 4; ++dd)
            kf[dd] = ldbf8(kbh + (size_t)tb * 2048 + dd * 512 + lane * 8);
    }

    for (int t = tb; t < te; ++t) {
        int kb = t * 32;
        // S^T = K Q^T (raw, unscaled): lane holds S[k-spread][q=ql], 16 regs
        f32x16 s = z16;
        #pragma unroll
        for (int dd = 0; dd < 4; ++dd) s = mfma32(kf[dd], qf[dd], s);

        if (t + 1 < te) {
            #pragma unroll
            for (int dd = 0; dd < 4; ++dd)
                kf[dd] = ldbf8(kbh + (size_t)(t + 1) * 2048 + dd * 512 + lane * 8);
        }
        // V fragments (K-slot permutation baked into the vfr layout)
        bf16x8 vf[2][2];
        #pragma unroll
        for (int d0 = 0; d0 < 2; ++d0)
            #pragma unroll
            for (int ks = 0; ks < 2; ++ks)
                vf[d0][ks] = ldbf8(vbh + (size_t)t * 2048 + d0 * 1024 + ks * 512 + lane * 8);

        // prefix-mask on raw S (tail tiles only; uniform branch)
        if (kb + 32 > valid) {
            #pragma unroll
            for (int r = 0; r < 16; ++r) {
                int kg = kb + (r & 3) + 8 * (r >> 2) + 4 * hi;
                if (kg >= valid) s[r] = -1e30f;
            }
        }
        // tree max over the lane's 16 raw values, then cross-half exchange
        float mx = fmaxf(fmaxf(fmaxf(s[0], s[1]), fmaxf(s[2], s[3])),
                         fmaxf(fmaxf(s[4], s[5]), fmaxf(s[6], s[7])));
        float my = fmaxf(fmaxf(fmaxf(s[8], s[9]), fmaxf(s[10], s[11])),
                         fmaxf(fmaxf(s[12], s[13]), fmaxf(s[14], s[15])));
        float pmax = fmaxf(mx, my);
        pmax = fmaxf(pmax, __shfl_xor(pmax, 32));
        float pm = pmax * QS2;   // into scaled (exp2) domain

        if (__any(pm > m)) {           // defer-max: skip rescale when possible
            float mn = fmaxf(m, pm);
            float scale = exp2fast(m - mn);
            m = mn;
            l *= scale;
            o0 *= scale; o1 *= scale;
        }

        // P = exp2(S*QS2 - m): one fma + one exp2 per element
        float negm = -m;
        float p[16];
        #pragma unroll
        for (int i = 0; i < 16; ++i)
            p[i] = exp2fast(__builtin_fmaf(s[i], QS2, negm));
        // tree row-sum + cross-half exchange
        float r0s = (p[0] + p[1]) + (p[2] + p[3]);
        float r1s = (p[4] + p[5]) + (p[6] + p[7]);
        float r2s = (p[8] + p[9]) + (p[10] + p[11]);
        float r3s = (p[12] + p[13]) + (p[14] + p[15]);
        float rs = (r0s + r1s) + (r2s + r3s);
        rs += __shfl_xor(rs, 32);
        l += rs;

        // pack to bf16 pairs; feed B-operand DIRECTLY (layouts match)
        union { unsigned u[4]; bf16x8 v; } A0, A1;
        A0.u[0] = pkbf(p[0],  p[1]);  A0.u[1] = pkbf(p[2],  p[3]);
        A0.u[2] = pkbf(p[4],  p[5]);  A0.u[3] = pkbf(p[6],  p[7]);
        A1.u[0] = pkbf(p[8],  p[9]);  A1.u[1] = pkbf(p[10], p[11]);
        A1.u[2] = pkbf(p[12], p[13]); A1.u[3] = pkbf(p[14], p[15]);

        o0 = mfma32(vf[0][0], A0.v, o0);
        o0 = mfma32(vf[0][1], A1.v, o0);
        o1 = mfma32(vf[1][0], A0.v, o1);
        o1 = mfma32(vf[1][1], A1.v, o1);
    }

    // merge the 4 partial flash states: waves 1..3 publish, wave 0 reduces
    if (w > 0) {
        int wi = w - 1;
        #pragma unroll
        for (int r = 0; r < 16; ++r) {
            oL[wi][lane][r]      = o0[r];
            oL[wi][lane][16 + r] = o1[r];
        }
        mL[wi][lane] = m;
        lL[wi][lane] = l;
    }
    __syncthreads();
    if (w > 0) return;

    float M = m;
    float mw[3], lw[3];
    #pragma unroll
    for (int j = 0; j < 3; ++j) {
        mw[j] = mL[j][lane];
        lw[j] = lL[j][lane];
        M = fmaxf(M, mw[j]);
    }
    float s0 = exp2fast(m - M);
    float L = l * s0;
    o0 *= s0; o1 *= s0;
    #pragma unroll
    for (int j = 0; j < 3; ++j) {
        float sj = exp2fast(mw[j] - M);
        L += lw[j] * sj;
        #pragma unroll
        for (int r = 0; r < 16; ++r) {
            o0[r] += sj * oL[j][lane][r];
            o1[r] += sj * oL[j][lane][16 + r];
        }
    }

    float inv = (L > 0.f) ? (1.f / L) : 0.f;
    unsigned short* ob = oatt + (size_t)(b * NT + q0 + ql) * NC + h * ND;
    #pragma unroll
    for (int g = 0; g < 4; ++g) {
        ushort4 s0v, s1v;
        s0v.x = f2bf(o0[4 * g + 0] * inv); s0v.y = f2bf(o0[4 * g + 1] * inv);
        s0v.z = f2bf(o0[4 * g + 2] * inv); s0v.w = f2bf(o0[4 * g + 3] * inv);
        s1v.x = f2bf(o1[4 * g + 0] * inv); s1v.y = f2bf(o1[4 * g + 1] * inv);
        s1v.z = f2bf(o1[4 * g + 2] * inv); s1v.w = f2bf(o1[4 * g + 3] * inv);
        *reinterpret_cast<ushort4*>(ob + g * 8 + 4 * hi)      = s0v;
        *reinterpret_cast<ushort4*>(ob + 32 + g * 8 + 4 * hi) = s1v;
    }
}

// ---------------------------------------------------------------------------
// Output projection, LDS-staged 2-phase; stores contiguous along T, fused mask.
// grid (24, 8), block 256.
__global__ __launch_bounds__(256) void gemm_out_kernel(
    const unsigned short* __restrict__ oatt, const unsigned short* __restrict__ wpb,
    const float* __restrict__ bp, const int* __restrict__ mask,
    float* __restrict__ out)
{
    __shared__ __align__(16) unsigned short lA[2][128 * BK];  // oatt tile (bt rows)
    __shared__ __align__(16) unsigned short lB[2][128 * BK];  // wp tile (o rows)

    int tid = threadIdx.x;
    int lane = tid & 63, w = tid >> 6;
    int mb  = blockIdx.x * 128;  // bt tile base
    int obb = blockIdx.y * 128;  // out-channel tile base

    int srow = w * 16 + (lane >> 2);
    const unsigned short* gA = oatt + (size_t)(mb + srow) * NC + (lane & 3) * 8;
    const unsigned short* gB = wpb + (size_t)(obb + srow) * NC + (lane & 3) * 8;
    unsigned short* lA0 = &lA[0][0] + w * 16 * BK;
    unsigned short* lB0 = &lB[0][0] + w * 16 * BK;

#define OUT_STAGE(buf, k0) do {                                       \
    gload16(gA + (k0),           lA0 + (buf) * 128 * BK);             \
    gload16(gA + (k0) + 64 * NC, lA0 + (buf) * 128 * BK + 64 * BK);   \
    gload16(gB + (k0),           lB0 + (buf) * 128 * BK);             \
    gload16(gB + (k0) + 64 * NC, lB0 + (buf) * 128 * BK + 64 * BK);   \
} while (0)

    int r0 = lane & 15, kg = lane >> 4;
    const unsigned short* fA = &lA[0][0] + ((w >> 1) * 64 + r0) * BK + kg * 8;
    const unsigned short* fB = &lB[0][0] + ((w & 1)  * 64 + r0) * BK + kg * 8;

    f32x4 acc[4][4];
    #pragma unroll
    for (int i = 0; i < 4; ++i)
        #pragma unroll
        for (int j = 0; j < 4; ++j) acc[i][j] = (f32x4){0.f, 0.f, 0.f, 0.f};

#define OUT_COMPUTE(buf) do {                                                  \
    bf16x8 a_[4], b_[4];                                                       \
    _Pragma("unroll") for (int i = 0; i < 4; ++i)                              \
        a_[i] = ldbf8(fA + (buf) * 128 * BK + i * 16 * BK);                    \
    _Pragma("unroll") for (int i = 0; i < 4; ++i)                              \
        b_[i] = ldbf8(fB + (buf) * 128 * BK + i * 16 * BK);                    \
    _Pragma("unroll") for (int mf = 0; mf < 4; ++mf)                           \
        _Pragma("unroll") for (int nf = 0; nf < 4; ++nf)                       \
            acc[mf][nf] = mfma16(a_[mf], b_[nf], acc[mf][nf]);                 \
} while (0)

    OUT_STAGE(0, 0);
    #pragma unroll 1
    for (int k0 = 0; k0 < NC - 2 * BK; k0 += 2 * BK) {
        OUT_STAGE(1, k0 + BK);
        WAITV(4); BAR();
        OUT_COMPUTE(0);
        BAR();
        OUT_STAGE(0, k0 + 2 * BK);
        WAITV(4); BAR();
        OUT_COMPUTE(1);
        BAR();
    }
    OUT_STAGE(1, NC - BK);
    WAITV(4); BAR();
    OUT_COMPUTE(0);
    WAITV(0); BAR();
    OUT_COMPUTE(1);

    int b_ = (int)(blockIdx.x >= 12);
    size_t obase = (size_t)b_ * NC * NT;
    #pragma unroll
    for (int mf = 0; mf < 4; ++mf) {
        int bt0 = mb + (w >> 1) * 64 + mf * 16 + kg * 4;
        int4 mv = *reinterpret_cast<const int4*>(mask + bt0);
        float m0 = mv.x ? 1.f : 0.f;
        float m1 = mv.y ? 1.f : 0.f;
        float m2 = mv.z ? 1.f : 0.f;
        float m3 = mv.w ? 1.f : 0.f;
        int t0 = bt0 - b_ * NT;
        #pragma unroll
        for (int nf = 0; nf < 4; ++nf) {
            int o = obb + (w & 1) * 64 + nf * 16 + r0;
            float bz = bp[o];
            f32x4 vv;
            vv[0] = (acc[mf][nf][0] + bz) * m0;
            vv[1] = (acc[mf][nf][1] + bz) * m1;
            vv[2] = (acc[mf][nf][2] + bz) * m2;
            vv[3] = (acc[mf][nf][3] + bz) * m3;
            *reinterpret_cast<f32x4*>(out + obase + (size_t)o * NT + t0) = vv;
        }
    }
#undef OUT_STAGE
#undef OUT_COMPUTE
}

// ---------------------------------------------------------------------------
__global__ __launch_bounds__(256) void maskout_kernel(const int* __restrict__ mask,
                                                      float* __restrict__ out)
{
    int i = blockIdx.x * 256 + threadIdx.x;
    if (i < NBT) out[(size_t)NB * NC * NT + i] = (mask[i] != 0) ? 1.f : 0.f;
}

// ---------------------------------------------------------------------------
extern "C" void kernel_launch(void* const* d_in, const int* in_sizes, int n_in,
                              void* d_out, int out_size, void* d_ws, size_t ws_size,
                              hipStream_t stream)
{
    const float* x    = (const float*)d_in[0];
    const float* y    = (const float*)d_in[1];
    const float* z    = (const float*)d_in[2];
    const int*   mask = (const int*)d_in[3];
    const float* qw   = (const float*)d_in[4];
    const float* kw   = (const float*)d_in[5];
    const float* vw   = (const float*)d_in[6];
    const float* qg   = (const float*)d_in[7];
    const float* qb   = (const float*)d_in[8];
    const float* kgm  = (const float*)d_in[9];
    const float* kbt  = (const float*)d_in[10];
    const float* vg   = (const float*)d_in[11];
    const float* vb   = (const float*)d_in[12];
    const float* wq   = (const float*)d_in[13];
    const float* bq   = (const float*)d_in[14];
    const float* wk   = (const float*)d_in[15];
    const float* bk   = (const float*)d_in[16];
    const float* wv   = (const float*)d_in[17];
    const float* bv   = (const float*)d_in[18];
    const float* wp   = (const float*)d_in[19];
    const float* bp   = (const float*)d_in[20];

    unsigned short* xn  = (unsigned short*)d_ws;
    unsigned short* yn  = xn + (size_t)NBT * NC;
    unsigned short* zn  = yn + (size_t)NBT * NC;
    unsigned short* qfr = zn + (size_t)NBT * NC;   // fragment layouts, same size
    unsigned short* kfr = qfr + (size_t)NBT * NC;
    unsigned short* vfr = kfr + (size_t)NBT * NC;
    unsigned short* wqb = vfr + (size_t)NBT * NC;
    unsigned short* wkb = wqb + (size_t)NC * NC;
    unsigned short* wvb = wkb + (size_t)NC * NC;
    unsigned short* wpb = wvb + (size_t)NC * NC;
    unsigned short* oatt = xn;  // xn dead after gemm_qkv; reuse for attention out

    float* out = (float*)d_out;

    wcvt_kernel<<<dim3(1024, 4), 256, 0, stream>>>(wq, wk, wv, wp, wqb, wkb, wvb, wpb);
    convln_kernel<<<dim3(NT / 16, NB, 3), 256, 0, stream>>>(
        x, y, z, qw, kw, vw, qg, qb, kgm, kbt, vg, vb, mask, xn, yn, zn);
    gemm_qkv_kernel<<<dim3(NBT / 128, NC / 128, 3), 256, 0, stream>>>(
        wqb, wkb, wvb, xn, yn, zn, bq, bk, bv, qfr, kfr, vfr);
    attn_kernel<<<dim3(48 * 32), 256, 0, stream>>>(qfr, kfr, vfr, mask, oatt);
    gemm_out_kernel<<<dim3(NBT / 128, NC / 128), 256, 0, stream>>>(oatt, wpb, bp, mask, out);
    maskout_kernel<<<dim3(NBT / 256), 256, 0, stream>>>(mask, out);
}

// Round 9
// 138.002 us; speedup vs baseline: 1.6206x; 1.0953x over previous
//
#include <hip/hip_runtime.h>
#include <hip/hip_bf16.h>

// Problem constants (from reference)
#define NB 2
#define NC 1024
#define NT 1536
#define NH 16
#define ND 64
#define NBT 3072   // NB*NT
#define LN_EPS 1e-5f
#define BK 32      // GEMM K-step
// attention scale folded with log2(e): softmax computed in exp2 domain
#define QS2 0.18033688011112042f   // 0.125 * log2(e)

typedef __attribute__((ext_vector_type(8))) __bf16 bf16x8;
typedef __attribute__((ext_vector_type(4))) float f32x4;
typedef __attribute__((ext_vector_type(16))) float f32x16;

__device__ __forceinline__ unsigned short f2bf(float f) {
    unsigned u = __float_as_uint(f);
    u += 0x7fffu + ((u >> 16) & 1u);   // round-to-nearest-even
    return (unsigned short)(u >> 16);
}
__device__ __forceinline__ float bf2f(unsigned short s) {
    return __uint_as_float(((unsigned)s) << 16);
}
// pack two f32 -> packed bf16x2 (compiler emits v_cvt_pk_bf16_f32)
__device__ __forceinline__ unsigned pkbf(float a, float b) {
    union { __bf16 h[2]; unsigned u; } r;
    r.h[0] = (__bf16)a; r.h[1] = (__bf16)b;
    return r.u;
}
__device__ __forceinline__ float exp2fast(float x) {
    return __builtin_amdgcn_exp2f(x);
}
__device__ __forceinline__ f32x4 mfma16(bf16x8 a, bf16x8 b, f32x4 c) {
    return __builtin_amdgcn_mfma_f32_16x16x32_bf16(a, b, c, 0, 0, 0);
}
__device__ __forceinline__ f32x16 mfma32(bf16x8 a, bf16x8 b, f32x16 c) {
    return __builtin_amdgcn_mfma_f32_32x32x16_bf16(a, b, c, 0, 0, 0);
}
__device__ __forceinline__ bf16x8 ldbf8(const unsigned short* p) {
    return *reinterpret_cast<const bf16x8*>(p);
}
// async global->LDS, 16B per lane; LDS dest = uniform base + lane*16
__device__ __forceinline__ void gload16(const void* g, void* l) {
    __builtin_amdgcn_global_load_lds(
        (const __attribute__((address_space(1))) void*)g,
        (__attribute__((address_space(3))) void*)l, 16, 0, 0);
}
#define WAITV(n) asm volatile("s_waitcnt vmcnt(" #n ")" ::: "memory")
#define BAR()    do { __builtin_amdgcn_s_barrier(); asm volatile("" ::: "memory"); } while (0)

// ---------------------------------------------------------------------------
// Fragment layouts (all 4 KB per (b,h,32-key/query tile), lane = hi*32+ql):
// q/k frag: tile*2048 + dd*512 + lane*8 + j   <- channel c = h*64+dd*16+hi*8+j
// v   frag: tile*2048 + d0*1024 + ks*512 + lane*8 + j  (K-slot permuted, see r5)
// Attn loads become fully-coalesced 1KB wave loads (kills L2 line amplification).
// ---------------------------------------------------------------------------

// Convert f32 1024x1024 weights -> bf16
__global__ __launch_bounds__(256) void wcvt_kernel(
    const float* __restrict__ w0, const float* __restrict__ w1,
    const float* __restrict__ w2, const float* __restrict__ w3,
    unsigned short* __restrict__ o0, unsigned short* __restrict__ o1,
    unsigned short* __restrict__ o2, unsigned short* __restrict__ o3)
{
    const float* src; unsigned short* dst;
    switch (blockIdx.y) {
        case 0: src = w0; dst = o0; break;
        case 1: src = w1; dst = o1; break;
        case 2: src = w2; dst = o2; break;
        default: src = w3; dst = o3; break;
    }
    int i = (blockIdx.x * 256 + threadIdx.x) * 4;
    float4 v = *reinterpret_cast<const float4*>(src + i);
    ushort4 r;
    r.x = f2bf(v.x); r.y = f2bf(v.y); r.z = f2bf(v.z); r.w = f2bf(v.w);
    *reinterpret_cast<ushort4*>(dst + i) = r;
}

// ---------------------------------------------------------------------------
// Depthwise conv3 (pad 1) -> mask -> channel LayerNorm -> bf16, [bt][c]
// Block = 1024 threads (16 waves): tt = tid&15 (t within tile), cc = tid>>4
// (64 channels per sweep, 16 sweeps). 2 blocks/CU = 32 waves (occupancy cap).
// Stats reduced per-wave via shfl_xor tree. LDS tile stride 1026 (513 odd ->
// conv-store and read phases are <=2-way bank aliased = free).
__global__ __launch_bounds__(1024) void convln_kernel(
    const float* __restrict__ x, const float* __restrict__ y, const float* __restrict__ z,
    const float* __restrict__ qw, const float* __restrict__ kw, const float* __restrict__ vw,
    const float* __restrict__ qg, const float* __restrict__ qb,
    const float* __restrict__ kgm, const float* __restrict__ kbt,
    const float* __restrict__ vg, const float* __restrict__ vb,
    const int* __restrict__ mask,
    unsigned short* __restrict__ xn, unsigned short* __restrict__ yn,
    unsigned short* __restrict__ zn)
{
    __shared__ unsigned short tile[16 * 1026];
    __shared__ float psum[16][65], psq[16][65];
    __shared__ float smu[16], srs[16];

    const float* src; const float* cw; const float* g; const float* be;
    unsigned short* dst;
    if (blockIdx.z == 0)      { src = x; cw = qw; g = qg;  be = qb;  dst = xn; }
    else if (blockIdx.z == 1) { src = y; cw = kw; g = kgm; be = kbt; dst = yn; }
    else                      { src = z; cw = vw; g = vg;  be = vb;  dst = zn; }

    int b  = blockIdx.y;
    int t0 = blockIdx.x * 16;
    int tid = threadIdx.x;
    int tt = tid & 15, cc = tid >> 4;   // cc = 0..63
    int t = t0 + tt;
    float mval = (mask[b * NT + t] != 0) ? 1.f : 0.f;

    const float* sb = src + (size_t)b * NC * NT;
    float sum = 0.f, ssq = 0.f;
    #pragma unroll 4
    for (int c0 = 0; c0 < NC; c0 += 64) {
        int c = c0 + cc;
        const float* xp = sb + (size_t)c * NT;
        float v0 = xp[t];
        float vm = __shfl_up(v0, 1, 16);
        float vp = __shfl_down(v0, 1, 16);
        if (tt == 0)  vm = (t > 0)      ? xp[t - 1] : 0.f;
        if (tt == 15) vp = (t + 1 < NT) ? xp[t + 1] : 0.f;
        float w0 = cw[c * 3], w1 = cw[c * 3 + 1], w2 = cw[c * 3 + 2];
        float conv = (w0 * vm + w1 * v0 + w2 * vp) * mval;
        tile[tt * 1026 + c] = f2bf(conv);
        sum += conv; ssq += conv * conv;
    }
    psum[tt][cc] = sum; psq[tt][cc] = ssq;
    __syncthreads();

    // wave w reduces t-row w (64 partials) via shfl tree
    int wv = tid >> 6, ln = tid & 63;
    float s = psum[wv][ln], q2 = psq[wv][ln];
    #pragma unroll
    for (int off = 32; off; off >>= 1) {
        s  += __shfl_xor(s, off);
        q2 += __shfl_xor(q2, off);
    }
    if (ln == 0) {
        float mu = s * (1.f / 1024.f);
        float var = q2 * (1.f / 1024.f) - mu * mu;
        smu[wv] = mu;
        srs[wv] = rsqrtf(var + LN_EPS);
    }
    __syncthreads();

    // write phase: thread owns channel c = tid; 128B/wave coalesced stores
    int c = tid;
    float gc = g[c], ec = be[c];
    unsigned short* db = dst + (size_t)(b * NT + t0) * NC + c;
    #pragma unroll 4
    for (int r = 0; r < 16; ++r) {
        float val = bf2f(tile[r * 1026 + c]);
        db[(size_t)r * NC] = f2bf((val - smu[r]) * srs[r] * gc + ec);
    }
}

// ---------------------------------------------------------------------------
// q/k/v projections, LDS-staged 2-phase double-buffered. Epilogue writes
// MFMA-fragment-major layouts consumed by attn (see layout comment above).
// grid (24, 8, 3), block 256 (4 waves, 2x2, 64x64/wave).
__global__ __launch_bounds__(256) void gemm_qkv_kernel(
    const unsigned short* __restrict__ wqb, const unsigned short* __restrict__ wkb,
    const unsigned short* __restrict__ wvb,
    const unsigned short* __restrict__ xn, const unsigned short* __restrict__ yn,
    const unsigned short* __restrict__ zn,
    const float* __restrict__ bq, const float* __restrict__ bk, const float* __restrict__ bv,
    unsigned short* __restrict__ qfr, unsigned short* __restrict__ kfr,
    unsigned short* __restrict__ vfr)
{
    __shared__ __align__(16) unsigned short lX[2][128 * BK];  // X tile (bt rows)
    __shared__ __align__(16) unsigned short lW[2][128 * BK];  // W tile (o rows)

    int which = blockIdx.z;
    const unsigned short* W = (which == 0) ? wqb : (which == 1) ? wkb : wvb;
    const unsigned short* X = (which == 0) ? xn : (which == 1) ? yn : zn;
    const float* bias = (which == 0) ? bq : (which == 1) ? bk : bv;

    int tid = threadIdx.x;
    int lane = tid & 63, w = tid >> 6;
    int nb = blockIdx.x * 128;   // bt tile base
    int ob = blockIdx.y * 128;   // out-channel tile base

    int srow = w * 16 + (lane >> 2);
    const unsigned short* gX = X + (size_t)(nb + srow) * NC + (lane & 3) * 8;
    const unsigned short* gW = W + (size_t)(ob + srow) * NC + (lane & 3) * 8;
    unsigned short* lX0 = &lX[0][0] + w * 16 * BK;
    unsigned short* lW0 = &lW[0][0] + w * 16 * BK;

#define QKV_STAGE(buf, k0) do {                                       \
    gload16(gX + (k0),           lX0 + (buf) * 128 * BK);             \
    gload16(gX + (k0) + 64 * NC, lX0 + (buf) * 128 * BK + 64 * BK);   \
    gload16(gW + (k0),           lW0 + (buf) * 128 * BK);             \
    gload16(gW + (k0) + 64 * NC, lW0 + (buf) * 128 * BK + 64 * BK);   \
} while (0)

    int r0 = lane & 15, kg = lane >> 4;
    const unsigned short* fW = &lW[0][0] + ((w & 1)  * 64 + r0) * BK + kg * 8;
    const unsigned short* fX = &lX[0][0] + ((w >> 1) * 64 + r0) * BK + kg * 8;

    f32x4 acc[4][4];
    #pragma unroll
    for (int i = 0; i < 4; ++i)
        #pragma unroll
        for (int j = 0; j < 4; ++j) acc[i][j] = (f32x4){0.f, 0.f, 0.f, 0.f};

#define QKV_COMPUTE(buf) do {                                                  \
    bf16x8 a_[4], b_[4];                                                       \
    _Pragma("unroll") for (int i = 0; i < 4; ++i)                              \
        a_[i] = ldbf8(fW + (buf) * 128 * BK + i * 16 * BK);                    \
    _Pragma("unroll") for (int i = 0; i < 4; ++i)                              \
        b_[i] = ldbf8(fX + (buf) * 128 * BK + i * 16 * BK);                    \
    _Pragma("unroll") for (int mf = 0; mf < 4; ++mf)                           \
        _Pragma("unroll") for (int nf = 0; nf < 4; ++nf)                       \
            acc[mf][nf] = mfma16(a_[mf], b_[nf], acc[mf][nf]);                 \
} while (0)

    QKV_STAGE(0, 0);
    #pragma unroll 1
    for (int k0 = 0; k0 < NC - 2 * BK; k0 += 2 * BK) {
        QKV_STAGE(1, k0 + BK);
        WAITV(4); BAR();
        QKV_COMPUTE(0);
        BAR();
        QKV_STAGE(0, k0 + 2 * BK);
        WAITV(4); BAR();
        QKV_COMPUTE(1);
        BAR();
    }
    QKV_STAGE(1, NC - BK);
    WAITV(4); BAR();
    QKV_COMPUTE(0);
    WAITV(0); BAR();
    QKV_COMPUTE(1);

    if (which < 2) {
        unsigned short* OUT = (which == 0) ? qfr : kfr;
        #pragma unroll
        for (int mf = 0; mf < 4; ++mf) {
            int o0 = ob + (w & 1) * 64 + mf * 16 + kg * 4;
            int h = o0 >> 6, c0 = o0 & 63;
            int dd = c0 >> 4, hi2 = (c0 >> 3) & 1, j0 = c0 & 7;
            float4 bz = *reinterpret_cast<const float4*>(bias + o0);
            #pragma unroll
            for (int nf = 0; nf < 4; ++nf) {
                int n = nb + (w >> 1) * 64 + nf * 16 + r0;
                int b_ = (n >= NT), t = n - b_ * NT;
                int t32 = t >> 5, ql = t & 31;
                size_t addr = ((size_t)((b_ * NH + h) * 48 + t32)) * 2048
                            + dd * 512 + (hi2 * 32 + ql) * 8 + j0;
                ushort4 st;
                st.x = f2bf(acc[mf][nf][0] + bz.x);
                st.y = f2bf(acc[mf][nf][1] + bz.y);
                st.z = f2bf(acc[mf][nf][2] + bz.z);
                st.w = f2bf(acc[mf][nf][3] + bz.w);
                *reinterpret_cast<ushort4*>(OUT + addr) = st;
            }
        }
    } else {
        #pragma unroll
        for (int mf = 0; mf < 4; ++mf) {
            int o0 = ob + (w & 1) * 64 + mf * 16 + kg * 4;
            int h = o0 >> 6;
            int dch0 = o0 & 63;
            int d0 = dch0 >> 5;
            #pragma unroll
            for (int nf = 0; nf < 4; ++nf) {
                int n = nb + (w >> 1) * 64 + nf * 16 + r0;
                int b_ = (n >= NT), t = n - b_ * NT;
                int t32 = t >> 5, kloc = t & 31;
                int ks = kloc >> 4, r16 = kloc & 15;
                int hi2 = (r16 >> 2) & 1;
                int j = (r16 & 3) + 4 * (r16 >> 3);
                size_t base = ((size_t)((b_ * NH + h) * 48 + t32)) * 2048
                            + d0 * 1024 + ks * 512 + hi2 * 256 + j;
                #pragma unroll
                for (int r = 0; r < 4; ++r) {
                    int ql = (dch0 + r) & 31;
                    vfr[base + ql * 8] = f2bf(acc[mf][nf][r] + bias[o0 + r]);
                }
            }
        }
    }
#undef QKV_STAGE
#undef QKV_COMPUTE
}

// ---------------------------------------------------------------------------
// Flash attention, block-level K-split, balanced XCD swizzle (r7), fragment-
// layout Q/K/V -> every load is one fully-coalesced 1KB wave load.
// grid 1536 (1-D), block 256 = 4 waves. Softmax in exp2 domain.
__global__ __launch_bounds__(256) void attn_kernel(
    const unsigned short* __restrict__ qfr, const unsigned short* __restrict__ kfr,
    const unsigned short* __restrict__ vfr, const int* __restrict__ mask,
    unsigned short* __restrict__ oatt)
{
    __shared__ float oL[3][64][33];
    __shared__ float mL[3][64], lL[3][64];

    // balanced XCD swizzle: each XCD owns 2 b=0 heads + 2 b=1 heads
    int bid = blockIdx.x;
    int xcd = bid & 7, slot = bid >> 3;        // 192 slots per XCD
    int hsel = slot / 48, qt = slot - hsel * 48;
    int bh = (hsel < 2) ? (2 * xcd + hsel) : (16 + 2 * xcd + (hsel - 2));
    int b = bh >> 4, h = bh & 15;
    int q0 = qt * 32;

    int lane = threadIdx.x & 63;
    int w = threadIdx.x >> 6;
    int ql = lane & 31;          // q column this lane owns
    int hi = lane >> 5;          // half-wave (k/d sub-slice)

    const int* mrow = mask + b * NT;
    int valid = 0;
    #pragma unroll
    for (int i = 0; i < NT / 64; ++i)
        valid += __popcll(__ballot(mrow[lane + 64 * i] != 0));
    if (q0 >= valid) return;     // masked q rows: oatt never observed downstream
    int ntiles = (valid + 31) >> 5;

    // this wave's K-chunk [tb, te)
    int per = ntiles >> 2, rem = ntiles & 3;
    int tb = w * per + (w < rem ? w : rem);
    int te = tb + per + (w < rem ? 1 : 0);

    const unsigned short* qtile = qfr + ((size_t)(bh * 48 + qt)) * 2048;
    bf16x8 qf[4];
    #pragma unroll
    for (int dd = 0; dd < 4; ++dd) qf[dd] = ldbf8(qtile + dd * 512 + lane * 8);

    const unsigned short* kbh = kfr + (size_t)bh * 48 * 2048;
    const unsigned short* vbh = vfr + (size_t)bh * 48 * 2048;

    const f32x16 z16 = {0.f,0.f,0.f,0.f, 0.f,0.f,0.f,0.f, 0.f,0.f,0.f,0.f, 0.f,0.f,0.f,0.f};
    f32x16 o0 = z16, o1 = z16;   // O^T: q = ql, d = blk*32 + (r&3)+8*(r>>2)+4*hi
    float m = -1e30f, l = 0.f;

    bf16x8 kf[4];
    if (tb < te) {
        #pragma unroll
        for (int dd = 0; dd < 4; ++dd)
            kf[dd] = ldbf8(kbh + (size_t)tb * 2048 + dd * 512 + lane * 8);
    }

    for (int t = tb; t < te; ++t) {
        int kb = t * 32;
        // S^T = K Q^T (raw, unscaled): lane holds S[k-spread][q=ql], 16 regs
        f32x16 s = z16;
        #pragma unroll
        for (int dd = 0; dd < 4; ++dd) s = mfma32(kf[dd], qf[dd], s);

        if (t + 1 < te) {
            #pragma unroll
            for (int dd = 0; dd < 4; ++dd)
                kf[dd] = ldbf8(kbh + (size_t)(t + 1) * 2048 + dd * 512 + lane * 8);
        }
        // V fragments (K-slot permutation baked into the vfr layout)
        bf16x8 vf[2][2];
        #pragma unroll
        for (int d0 = 0; d0 < 2; ++d0)
            #pragma unroll
            for (int ks = 0; ks < 2; ++ks)
                vf[d0][ks] = ldbf8(vbh + (size_t)t * 2048 + d0 * 1024 + ks * 512 + lane * 8);

        // prefix-mask on raw S (tail tiles only; uniform branch)
        if (kb + 32 > valid) {
            #pragma unroll
            for (int r = 0; r < 16; ++r) {
                int kg = kb + (r & 3) + 8 * (r >> 2) + 4 * hi;
                if (kg >= valid) s[r] = -1e30f;
            }
        }
        // tree max over the lane's 16 raw values, then cross-half exchange
        float mx = fmaxf(fmaxf(fmaxf(s[0], s[1]), fmaxf(s[2], s[3])),
                         fmaxf(fmaxf(s[4], s[5]), fmaxf(s[6], s[7])));
        float my = fmaxf(fmaxf(fmaxf(s[8], s[9]), fmaxf(s[10], s[11])),
                         fmaxf(fmaxf(s[12], s[13]), fmaxf(s[14], s[15])));
        float pmax = fmaxf(mx, my);
        pmax = fmaxf(pmax, __shfl_xor(pmax, 32));
        float pm = pmax * QS2;   // into scaled (exp2) domain

        if (__any(pm > m)) {           // defer-max: skip rescale when possible
            float mn = fmaxf(m, pm);
            float scale = exp2fast(m - mn);
            m = mn;
            l *= scale;
            o0 *= scale; o1 *= scale;
        }

        // P = exp2(S*QS2 - m): one fma + one exp2 per element
        float negm = -m;
        float p[16];
        #pragma unroll
        for (int i = 0; i < 16; ++i)
            p[i] = exp2fast(__builtin_fmaf(s[i], QS2, negm));
        // tree row-sum + cross-half exchange
        float r0s = (p[0] + p[1]) + (p[2] + p[3]);
        float r1s = (p[4] + p[5]) + (p[6] + p[7]);
        float r2s = (p[8] + p[9]) + (p[10] + p[11]);
        float r3s = (p[12] + p[13]) + (p[14] + p[15]);
        float rs = (r0s + r1s) + (r2s + r3s);
        rs += __shfl_xor(rs, 32);
        l += rs;

        // pack to bf16 pairs; feed B-operand DIRECTLY (layouts match)
        union { unsigned u[4]; bf16x8 v; } A0, A1;
        A0.u[0] = pkbf(p[0],  p[1]);  A0.u[1] = pkbf(p[2],  p[3]);
        A0.u[2] = pkbf(p[4],  p[5]);  A0.u[3] = pkbf(p[6],  p[7]);
        A1.u[0] = pkbf(p[8],  p[9]);  A1.u[1] = pkbf(p[10], p[11]);
        A1.u[2] = pkbf(p[12], p[13]); A1.u[3] = pkbf(p[14], p[15]);

        o0 = mfma32(vf[0][0], A0.v, o0);
        o0 = mfma32(vf[0][1], A1.v, o0);
        o1 = mfma32(vf[1][0], A0.v, o1);
        o1 = mfma32(vf[1][1], A1.v, o1);
    }

    // merge the 4 partial flash states: waves 1..3 publish, wave 0 reduces
    if (w > 0) {
        int wi = w - 1;
        #pragma unroll
        for (int r = 0; r < 16; ++r) {
            oL[wi][lane][r]      = o0[r];
            oL[wi][lane][16 + r] = o1[r];
        }
        mL[wi][lane] = m;
        lL[wi][lane] = l;
    }
    __syncthreads();
    if (w > 0) return;

    float M = m;
    float mw[3], lw[3];
    #pragma unroll
    for (int j = 0; j < 3; ++j) {
        mw[j] = mL[j][lane];
        lw[j] = lL[j][lane];
        M = fmaxf(M, mw[j]);
    }
    float s0 = exp2fast(m - M);
    float L = l * s0;
    o0 *= s0; o1 *= s0;
    #pragma unroll
    for (int j = 0; j < 3; ++j) {
        float sj = exp2fast(mw[j] - M);
        L += lw[j] * sj;
        #pragma unroll
        for (int r = 0; r < 16; ++r) {
            o0[r] += sj * oL[j][lane][r];
            o1[r] += sj * oL[j][lane][16 + r];
        }
    }

    float inv = (L > 0.f) ? (1.f / L) : 0.f;
    unsigned short* ob = oatt + (size_t)(b * NT + q0 + ql) * NC + h * ND;
    #pragma unroll
    for (int g = 0; g < 4; ++g) {
        ushort4 s0v, s1v;
        s0v.x = f2bf(o0[4 * g + 0] * inv); s0v.y = f2bf(o0[4 * g + 1] * inv);
        s0v.z = f2bf(o0[4 * g + 2] * inv); s0v.w = f2bf(o0[4 * g + 3] * inv);
        s1v.x = f2bf(o1[4 * g + 0] * inv); s1v.y = f2bf(o1[4 * g + 1] * inv);
        s1v.z = f2bf(o1[4 * g + 2] * inv); s1v.w = f2bf(o1[4 * g + 3] * inv);
        *reinterpret_cast<ushort4*>(ob + g * 8 + 4 * hi)      = s0v;
        *reinterpret_cast<ushort4*>(ob + 32 + g * 8 + 4 * hi) = s1v;
    }
}

// ---------------------------------------------------------------------------
// Output projection, LDS-staged 2-phase; stores contiguous along T, fused mask.
// grid (24, 8), block 256.
__global__ __launch_bounds__(256) void gemm_out_kernel(
    const unsigned short* __restrict__ oatt, const unsigned short* __restrict__ wpb,
    const float* __restrict__ bp, const int* __restrict__ mask,
    float* __restrict__ out)
{
    __shared__ __align__(16) unsigned short lA[2][128 * BK];  // oatt tile (bt rows)
    __shared__ __align__(16) unsigned short lB[2][128 * BK];  // wp tile (o rows)

    int tid = threadIdx.x;
    int lane = tid & 63, w = tid >> 6;
    int mb  = blockIdx.x * 128;  // bt tile base
    int obb = blockIdx.y * 128;  // out-channel tile base

    int srow = w * 16 + (lane >> 2);
    const unsigned short* gA = oatt + (size_t)(mb + srow) * NC + (lane & 3) * 8;
    const unsigned short* gB = wpb + (size_t)(obb + srow) * NC + (lane & 3) * 8;
    unsigned short* lA0 = &lA[0][0] + w * 16 * BK;
    unsigned short* lB0 = &lB[0][0] + w * 16 * BK;

#define OUT_STAGE(buf, k0) do {                                       \
    gload16(gA + (k0),           lA0 + (buf) * 128 * BK);             \
    gload16(gA + (k0) + 64 * NC, lA0 + (buf) * 128 * BK + 64 * BK);   \
    gload16(gB + (k0),           lB0 + (buf) * 128 * BK);             \
    gload16(gB + (k0) + 64 * NC, lB0 + (buf) * 128 * BK + 64 * BK);   \
} while (0)

    int r0 = lane & 15, kg = lane >> 4;
    const unsigned short* fA = &lA[0][0] + ((w >> 1) * 64 + r0) * BK + kg * 8;
    const unsigned short* fB = &lB[0][0] + ((w & 1)  * 64 + r0) * BK + kg * 8;

    f32x4 acc[4][4];
    #pragma unroll
    for (int i = 0; i < 4; ++i)
        #pragma unroll
        for (int j = 0; j < 4; ++j) acc[i][j] = (f32x4){0.f, 0.f, 0.f, 0.f};

#define OUT_COMPUTE(buf) do {                                                  \
    bf16x8 a_[4], b_[4];                                                       \
    _Pragma("unroll") for (int i = 0; i < 4; ++i)                              \
        a_[i] = ldbf8(fA + (buf) * 128 * BK + i * 16 * BK);                    \
    _Pragma("unroll") for (int i = 0; i < 4; ++i)                              \
        b_[i] = ldbf8(fB + (buf) * 128 * BK + i * 16 * BK);                    \
    _Pragma("unroll") for (int mf = 0; mf < 4; ++mf)                           \
        _Pragma("unroll") for (int nf = 0; nf < 4; ++nf)                       \
            acc[mf][nf] = mfma16(a_[mf], b_[nf], acc[mf][nf]);                 \
} while (0)

    OUT_STAGE(0, 0);
    #pragma unroll 1
    for (int k0 = 0; k0 < NC - 2 * BK; k0 += 2 * BK) {
        OUT_STAGE(1, k0 + BK);
        WAITV(4); BAR();
        OUT_COMPUTE(0);
        BAR();
        OUT_STAGE(0, k0 + 2 * BK);
        WAITV(4); BAR();
        OUT_COMPUTE(1);
        BAR();
    }
    OUT_STAGE(1, NC - BK);
    WAITV(4); BAR();
    OUT_COMPUTE(0);
    WAITV(0); BAR();
    OUT_COMPUTE(1);

    int b_ = (int)(blockIdx.x >= 12);
    size_t obase = (size_t)b_ * NC * NT;
    #pragma unroll
    for (int mf = 0; mf < 4; ++mf) {
        int bt0 = mb + (w >> 1) * 64 + mf * 16 + kg * 4;
        int4 mv = *reinterpret_cast<const int4*>(mask + bt0);
        float m0 = mv.x ? 1.f : 0.f;
        float m1 = mv.y ? 1.f : 0.f;
        float m2 = mv.z ? 1.f : 0.f;
        float m3 = mv.w ? 1.f : 0.f;
        int t0 = bt0 - b_ * NT;
        #pragma unroll
        for (int nf = 0; nf < 4; ++nf) {
            int o = obb + (w & 1) * 64 + nf * 16 + r0;
            float bz = bp[o];
            f32x4 vv;
            vv[0] = (acc[mf][nf][0] + bz) * m0;
            vv[1] = (acc[mf][nf][1] + bz) * m1;
            vv[2] = (acc[mf][nf][2] + bz) * m2;
            vv[3] = (acc[mf][nf][3] + bz) * m3;
            *reinterpret_cast<f32x4*>(out + obase + (size_t)o * NT + t0) = vv;
        }
    }
#undef OUT_STAGE
#undef OUT_COMPUTE
}

// ---------------------------------------------------------------------------
__global__ __launch_bounds__(256) void maskout_kernel(const int* __restrict__ mask,
                                                      float* __restrict__ out)
{
    int i = blockIdx.x * 256 + threadIdx.x;
    if (i < NBT) out[(size_t)NB * NC * NT + i] = (mask[i] != 0) ? 1.f : 0.f;
}

// ---------------------------------------------------------------------------
extern "C" void kernel_launch(void* const* d_in, const int* in_sizes, int n_in,
                              void* d_out, int out_size, void* d_ws, size_t ws_size,
                              hipStream_t stream)
{
    const float* x    = (const float*)d_in[0];
    const float* y    = (const float*)d_in[1];
    const float* z    = (const float*)d_in[2];
    const int*   mask = (const int*)d_in[3];
    const float* qw   = (const float*)d_in[4];
    const float* kw   = (const float*)d_in[5];
    const float* vw   = (const float*)d_in[6];
    const float* qg   = (const float*)d_in[7];
    const float* qb   = (const float*)d_in[8];
    const float* kgm  = (const float*)d_in[9];
    const float* kbt  = (const float*)d_in[10];
    const float* vg   = (const float*)d_in[11];
    const float* vb   = (const float*)d_in[12];
    const float* wq   = (const float*)d_in[13];
    const float* bq   = (const float*)d_in[14];
    const float* wk   = (const float*)d_in[15];
    const float* bk   = (const float*)d_in[16];
    const float* wv   = (const float*)d_in[17];
    const float* bv   = (const float*)d_in[18];
    const float* wp   = (const float*)d_in[19];
    const float* bp   = (const float*)d_in[20];

    unsigned short* xn  = (unsigned short*)d_ws;
    unsigned short* yn  = xn + (size_t)NBT * NC;
    unsigned short* zn  = yn + (size_t)NBT * NC;
    unsigned short* qfr = zn + (size_t)NBT * NC;   // fragment layouts, same size
    unsigned short* kfr = qfr + (size_t)NBT * NC;
    unsigned short* vfr = kfr + (size_t)NBT * NC;
    unsigned short* wqb = vfr + (size_t)NBT * NC;
    unsigned short* wkb = wqb + (size_t)NC * NC;
    unsigned short* wvb = wkb + (size_t)NC * NC;
    unsigned short* wpb = wvb + (size_t)NC * NC;
    unsigned short* oatt = xn;  // xn dead after gemm_qkv; reuse for attention out

    float* out = (float*)d_out;

    wcvt_kernel<<<dim3(1024, 4), 256, 0, stream>>>(wq, wk, wv, wp, wqb, wkb, wvb, wpb);
    convln_kernel<<<dim3(NT / 16, NB, 3), 1024, 0, stream>>>(
        x, y, z, qw, kw, vw, qg, qb, kgm, kbt, vg, vb, mask, xn, yn, zn);
    gemm_qkv_kernel<<<dim3(NBT / 128, NC / 128, 3), 256, 0, stream>>>(
        wqb, wkb, wvb, xn, yn, zn, bq, bk, bv, qfr, kfr, vfr);
    attn_kernel<<<dim3(48 * 32), 256, 0, stream>>>(qfr, kfr, vfr, mask, oatt);
    gemm_out_kernel<<<dim3(NBT / 128, NC / 128), 256, 0, stream>>>(oatt, wpb, bp, mask, out);
    maskout_kernel<<<dim3(NBT / 256), 256, 0, stream>>>(mask, out);
}